// Round 2
// baseline (2663.104 us; speedup 1.0000x reference)
//
#include <hip/hip_runtime.h>

#define SEQ 512
#define CAN 0x7FC0DEADu   // qNaN payload canary: never produced by finite LSTM math
#define NRECUR 256
#define NGEMM  256
#define CNT_FULL 16384u   // 64 tiles/chunk * 256 threads: per-thread RELEASE adds

#define LDA(p)   __hip_atomic_load((p), __ATOMIC_RELAXED, __HIP_MEMORY_SCOPE_AGENT)
#define STA(p,v) __hip_atomic_store((p), (v), __ATOMIC_RELAXED, __HIP_MEMORY_SCOPE_AGENT)

__device__ __forceinline__ bool has_can(unsigned long long v) {
    return ((unsigned)v == CAN) | ((unsigned)(v >> 32) == CAN);
}

// zero flags+chunk counters, canary-fill both per-step h handoff buffers
__global__ __launch_bounds__(256) void init_bufs(
    unsigned* __restrict__ flags, unsigned* __restrict__ hist_u,
    unsigned* __restrict__ h1_u)
{
    int i = blockIdx.x * 256 + threadIdx.x;
    if (i < 2080) flags[i] = 0u;   // flags0[1024] flags1[1024] g0cnt[16] g1cnt[16]
    int stride = gridDim.x * 256;
    for (int k = i; k < 512 * 2048; k += stride) {
        hist_u[k] = CAN;
        h1_u[k]   = CAN;
    }
}

// ---------------- GEMM tile: G[64,64] += X[64,K] @ W[64,K]^T + bias --------
// XATOMIC: X is being produced by the recurrence in this same kernel -> read
// via agent-scope (LLC) loads with canary retry (flags are fire-and-forget,
// data may trail the flag). W/bias are kernel inputs (cached plain loads).
// G stores are agent-scope (visible to other XCDs' gated loads); each thread
// then RELEASE-increments the chunk counter, so cnt==CNT_FULL proves every
// thread's stores reached LLC (no cross-wave drain assumption needed).
template<bool XATOMIC>
__device__ void gemm_tile(const float* __restrict__ X, const float* __restrict__ W,
                          const float* __restrict__ bias, float* __restrict__ G,
                          int m0, int n0, int K,
                          float (*__restrict__ Xs)[65], float (*__restrict__ Ws)[65])
{
    int tid = threadIdx.x;
    int tx = tid & 15, ty = tid >> 4;
    int row = tid >> 2, kq = (tid & 3) << 2;
    float acc[4][4] = {};
    for (int k0 = 0; k0 < K; k0 += 16) {
        float4 vx;
        if (XATOMIC) {
            const unsigned long long* xp =
                (const unsigned long long*)(X + (size_t)(m0 + row) * K + k0 + kq);
            unsigned long long u0, u1;
            for (;;) {
                u0 = LDA(xp); u1 = LDA(xp + 1);
                if (!(has_can(u0) | has_can(u1))) break;
            }
            vx.x = __uint_as_float((unsigned)u0);
            vx.y = __uint_as_float((unsigned)(u0 >> 32));
            vx.z = __uint_as_float((unsigned)u1);
            vx.w = __uint_as_float((unsigned)(u1 >> 32));
        } else {
            vx = *(const float4*)(X + (size_t)(m0 + row) * K + k0 + kq);
        }
        Xs[kq + 0][row] = vx.x; Xs[kq + 1][row] = vx.y;
        Xs[kq + 2][row] = vx.z; Xs[kq + 3][row] = vx.w;
        float4 vw = *(const float4*)(W + (size_t)(n0 + row) * K + k0 + kq);
        Ws[kq + 0][row] = vw.x; Ws[kq + 1][row] = vw.y;
        Ws[kq + 2][row] = vw.z; Ws[kq + 3][row] = vw.w;
        __syncthreads();
        #pragma unroll
        for (int k = 0; k < 16; ++k) {
            float a[4], b[4];
            #pragma unroll
            for (int i = 0; i < 4; ++i) a[i] = Xs[k][ty * 4 + i];
            #pragma unroll
            for (int j = 0; j < 4; ++j) b[j] = Ws[k][tx * 4 + j];
            #pragma unroll
            for (int i = 0; i < 4; ++i)
                #pragma unroll
                for (int j = 0; j < 4; ++j)
                    acc[i][j] = fmaf(a[i], b[j], acc[i][j]);
        }
        __syncthreads();
    }
    #pragma unroll
    for (int i = 0; i < 4; ++i) {
        int m = m0 + ty * 4 + i;
        #pragma unroll
        for (int j = 0; j < 4; ++j) {
            int n = n0 + tx * 4 + j;
            STA(&G[(size_t)m * 4096 + n], acc[i][j] + bias[n]);
        }
    }
}

// wait until outs0 rows [64rc, 64rc+64) fully published AND consumed by
// recur-0: fwd flags >= 64rc+64, bwd flags >= 512-64rc. Long sleeps: slack.
__device__ void wait_outs0(const unsigned* __restrict__ flags0, int rc)
{
    unsigned tf = (unsigned)(64 * rc + 64);
    unsigned tb = (unsigned)(512 - 64 * rc);
    int tid = threadIdx.x;
    if (tid < 64) {
        const unsigned* ff = flags0 + tid * 4;          // fwd gblk tid / tid+64
        const unsigned* fb = flags0 + 512 + tid * 4;    // bwd
        for (;;) {
            unsigned a0 = LDA(ff), a1 = LDA(ff + 256);
            unsigned b0 = LDA(fb), b1 = LDA(fb + 256);
            if (__all(a0 >= tf && a1 >= tf && b0 >= tb && b1 >= tb)) break;
            __builtin_amdgcn_s_sleep(64);
        }
    }
    __syncthreads();
}

// ---------------- Recurrence cell (proven protocol from prior session) ------
// R1 fix: the G-readiness gate is checked ONCE PER CHUNK (it&63==0; chunk
// index t>>6 is constant across each 64-step span in both directions), not
// every step. R0's per-step dependent gcnt load put one LLC RTT on wave0's
// critical path each step (~0.5us/step = the whole R0 regression). gpre is
// back to a fire-and-forget LLC load hidden under the h-flag poll.
__device__ void recur_cell(
    const float* __restrict__ Gin, const float* __restrict__ Wh,
    float* __restrict__ hio, float* __restrict__ finh, float* __restrict__ finc,
    unsigned* __restrict__ myflags, const unsigned* __restrict__ gcnt,
    int cell, int gblk, float4* __restrict__ h4s, float* __restrict__ part)
{
    int tid = threadIdx.x;
    int j0 = gblk << 3;
    int tr = tid & 31, chunk = tid >> 5;
    int grow = ((tr >> 3) << 10) + j0 + (tr & 7);   // gate row in [0,4096)

    // W_hh slice -> regs (one-time), pinned via opaque asm (R3/R4 lesson)
    const float4* wrow = (const float4*)(Wh + (size_t)grow * 1024) + (chunk << 5);
    float4 w[32];
    #pragma unroll
    for (int i = 0; i < 32; ++i) w[i] = wrow[i];
    #pragma unroll
    for (int i = 0; i < 32; ++i)
        asm volatile("" : "+v"(w[i].x), "+v"(w[i].y), "+v"(w[i].z), "+v"(w[i].w));

    float cprev = 0.f;

    for (int it = 0; it < SEQ; ++it) {
        int t = cell ? (SEQ - 1 - it) : it;

        // per-chunk G gate: 8 dependent checks per 512 steps (R1 lesson)
        if ((it & 63) == 0 && tid < 32) {
            const unsigned* cp = gcnt + (t >> 6);
            while (LDA(cp) < CNT_FULL) __builtin_amdgcn_s_sleep(8);
        }
        // fire-and-forget prefetch, hidden under the h poll
        float gpre = 0.f;
        if (tid < 32)
            gpre = __uint_as_float(LDA((const unsigned*)Gin + (size_t)t * 4096 + grow));

        if (it == 0) {
            h4s[tid] = make_float4(0.f, 0.f, 0.f, 0.f);
        } else {
            if (tid < 64) {   // wave0 polls all 128 flags (2 per lane)
                const unsigned* f0 = myflags + tid * 4;
                const unsigned* f1 = myflags + 256 + tid * 4;
                unsigned tgt = (unsigned)it;
                for (;;) {
                    unsigned a = LDA(f0);
                    unsigned b = LDA(f1);
                    if (__all(a >= tgt && b >= tgt)) break;
                    __builtin_amdgcn_s_sleep(1);
                }
            }
            __syncthreads();
            const float* hp = cell ? (hio + (size_t)(t + 1) * 2048 + 1024)
                                   : (hio + (size_t)(t - 1) * 2048);
            const unsigned long long* hp64 = (const unsigned long long*)hp;
            unsigned long long u0, u1;
            for (;;) {   // canary-validated bulk load (retry rare)
                u0 = LDA(hp64 + 2 * tid);
                u1 = LDA(hp64 + 2 * tid + 1);
                if (!(has_can(u0) | has_can(u1))) break;
            }
            h4s[tid] = make_float4(__uint_as_float((unsigned)u0),
                                   __uint_as_float((unsigned)(u0 >> 32)),
                                   __uint_as_float((unsigned)u1),
                                   __uint_as_float((unsigned)(u1 >> 32)));
        }
        __syncthreads();

        // matvec: row tr, cols [chunk*128, +128); 4 independent acc chains
        float a0 = 0.f, a1 = 0.f, a2 = 0.f, a3 = 0.f;
        const float4* hc = h4s + (chunk << 5);
        #pragma unroll
        for (int i = 0; i < 32; i += 4) {
            float4 h0 = hc[i], h1 = hc[i + 1], h2 = hc[i + 2], h3 = hc[i + 3];
            a0 = fmaf(w[i].x, h0.x, a0);     a0 = fmaf(w[i].y, h0.y, a0);
            a0 = fmaf(w[i].z, h0.z, a0);     a0 = fmaf(w[i].w, h0.w, a0);
            a1 = fmaf(w[i+1].x, h1.x, a1);   a1 = fmaf(w[i+1].y, h1.y, a1);
            a1 = fmaf(w[i+1].z, h1.z, a1);   a1 = fmaf(w[i+1].w, h1.w, a1);
            a2 = fmaf(w[i+2].x, h2.x, a2);   a2 = fmaf(w[i+2].y, h2.y, a2);
            a2 = fmaf(w[i+2].z, h2.z, a2);   a2 = fmaf(w[i+2].w, h2.w, a2);
            a3 = fmaf(w[i+3].x, h3.x, a3);   a3 = fmaf(w[i+3].y, h3.y, a3);
            a3 = fmaf(w[i+3].z, h3.z, a3);   a3 = fmaf(w[i+3].w, h3.w, a3);
        }
        part[chunk * 33 + tr] = (a0 + a1) + (a2 + a3);
        __syncthreads();

        if (tid < 32) {
            float v = gpre;
            #pragma unroll
            for (int k = 0; k < 8; ++k) v += part[k * 33 + tid];
            bool isg = (tid >> 3) == 2;           // gate g -> tanh
            float s = isg ? 2.f : 1.f;
            float e = __expf(-s * v);
            float r = 1.f / (1.f + e);
            float a = isg ? 2.f * r - 1.f : r;
            float si = __shfl(a, (tid & 7) + 0);
            float sf = __shfl(a, (tid & 7) + 8);
            float tg = __shfl(a, (tid & 7) + 16);
            float so = __shfl(a, (tid & 7) + 24);
            if (tid < 8) {
                float cnew = sf * cprev + si * tg;
                float e2 = __expf(-2.f * cnew);
                float hnew = so * (2.f / (1.f + e2) - 1.f);
                cprev = cnew;
                int j = j0 + tid;
                STA(&hio[(size_t)t * 2048 + cell * 1024 + j], hnew);
                if (it == SEQ - 1) {
                    STA(&finh[j], hnew);
                    STA(&finc[j], cnew);
                }
            }
            if (tid == 0)   // every step incl. 511 (value 512): GEMM-1 gate
                STA(&myflags[gblk * 4], (unsigned)(it + 1));
        }
    }
}

// ---------------- Fused pipeline kernel -------------------------------------
// 512 cooperative blocks, 2/CU. Blocks [0,256): recurrence (layer0 then
// layer1, setprio 1). Blocks [256,512): GEMM workers streaming G0 then G1 in
// 64x64 tiles. G1 pair k = (fwd rc=k, bwd rc=7-k) becomes available at
// recur-0 step max(64k+64, 512-64k); korder lists pairs by availability so
// each worker's gated list is monotone -> middle chunks stream DURING recur0
// (R1 fix: ascending k made every worker block on the last-available pair,
// bursting all of G1 at the layer transition). G1 reuses G0's buffers: the
// readiness gate also proves the overwritten G0 chunk was consumed.
__constant__ int korder[8] = {3, 4, 2, 5, 1, 6, 0, 7};

__global__ __launch_bounds__(256, 2) void lstm_fused(
    const float* __restrict__ x,
    const float* __restrict__ w_ih0f, const float* __restrict__ w_hh0f, const float* __restrict__ b0f,
    const float* __restrict__ w_ih0b, const float* __restrict__ w_hh0b, const float* __restrict__ b0b,
    const float* __restrict__ w_ih1f, const float* __restrict__ w_hh1f, const float* __restrict__ b1f,
    const float* __restrict__ w_ih1b, const float* __restrict__ w_hh1b, const float* __restrict__ b1b,
    float* __restrict__ G0f, float* __restrict__ G0b,
    float* __restrict__ hist, float* __restrict__ h1buf,
    float* __restrict__ out,
    unsigned* __restrict__ flags0, unsigned* __restrict__ flags1,
    unsigned* __restrict__ g0cnt, unsigned* __restrict__ g1cnt)
{
    __shared__ float4 h4s[256];
    __shared__ float part[8 * 33];
    __shared__ float Xs[16][65];
    __shared__ float Ws[16][65];

    int bid = blockIdx.x;
    if (bid < NRECUR) {
        __builtin_amdgcn_s_setprio(1);   // keep recurrence issue priority
        int cell = (bid >> 7) & 1;
        int gblk = bid & 127;
        recur_cell(cell ? G0b : G0f, cell ? w_hh0b : w_hh0f, hist,
                   out + cell * 1024, out + 4096 + cell * 1024,
                   flags0 + cell * 512, g0cnt + cell * 8, cell, gblk, h4s, part);
        recur_cell(cell ? G0b : G0f, cell ? w_hh1b : w_hh1f, h1buf,   // G1 aliases G0
                   out + 2048 + cell * 1024, out + 4096 + 2048 + cell * 1024,
                   flags1 + cell * 512, g1cnt + cell * 8, cell, gblk, h4s, part);
    } else {
        int gid = bid - NRECUR;
        // G0: no input gate (x is a kernel input); ends-first order
        for (int idx = gid; idx < 1024; idx += NGEMM) {
            int k = idx >> 7, half = (idx >> 6) & 1, cc = idx & 63;
            int rc = half ? (7 - k) : k;
            gemm_tile<false>(x, half ? w_ih0b : w_ih0f, half ? b0b : b0f,
                             half ? G0b : G0f, rc * 64, cc * 64, 1024, Xs, Ws);
            __hip_atomic_fetch_add(&g0cnt[half * 8 + rc], 1u,
                                   __ATOMIC_RELEASE, __HIP_MEMORY_SCOPE_AGENT);
        }
        // G1: gated on recur-0 progress; availability order (korder)
        for (int idx = gid; idx < 1024; idx += NGEMM) {
            int k = korder[idx >> 7], half = (idx >> 6) & 1, cc = idx & 63;
            int rc = half ? (7 - k) : k;
            wait_outs0(flags0, rc);
            gemm_tile<true>(hist, half ? w_ih1b : w_ih1f, half ? b1b : b1f,
                            half ? G0b : G0f, rc * 64, cc * 64, 2048, Xs, Ws);
            __hip_atomic_fetch_add(&g1cnt[half * 8 + rc], 1u,
                                   __ATOMIC_RELEASE, __HIP_MEMORY_SCOPE_AGENT);
        }
    }
}

// ================= Fallback path (proven 4-kernel version) ==================
__global__ __launch_bounds__(256) void gemm_bias2(
    const float* __restrict__ X,
    const float* __restrict__ Wf, const float* __restrict__ Wb,
    const float* __restrict__ biasf, const float* __restrict__ biasb,
    float* __restrict__ Gf, float* __restrict__ Gb,
    int M, int N, int K)
{
    const float* W    = blockIdx.z ? Wb : Wf;
    const float* bias = blockIdx.z ? biasb : biasf;
    float*       G    = blockIdx.z ? Gb : Gf;
    __shared__ float Xs[16][65];
    __shared__ float Ws[16][65];
    int tid = threadIdx.x;
    int tx = tid & 15, ty = tid >> 4;
    int m0 = blockIdx.y * 64, n0 = blockIdx.x * 64;
    float acc[4][4] = {};
    for (int k0 = 0; k0 < K; k0 += 16) {
        int row = tid >> 2, kq = (tid & 3) << 2;
        float4 vx = *(const float4*)(X + (size_t)(m0 + row) * K + k0 + kq);
        Xs[kq + 0][row] = vx.x; Xs[kq + 1][row] = vx.y;
        Xs[kq + 2][row] = vx.z; Xs[kq + 3][row] = vx.w;
        float4 vw = *(const float4*)(W + (size_t)(n0 + row) * K + k0 + kq);
        Ws[kq + 0][row] = vw.x; Ws[kq + 1][row] = vw.y;
        Ws[kq + 2][row] = vw.z; Ws[kq + 3][row] = vw.w;
        __syncthreads();
        #pragma unroll
        for (int k = 0; k < 16; ++k) {
            float a[4], b[4];
            #pragma unroll
            for (int i = 0; i < 4; ++i) a[i] = Xs[k][ty * 4 + i];
            #pragma unroll
            for (int j = 0; j < 4; ++j) b[j] = Ws[k][tx * 4 + j];
            #pragma unroll
            for (int i = 0; i < 4; ++i)
                #pragma unroll
                for (int j = 0; j < 4; ++j)
                    acc[i][j] = fmaf(a[i], b[j], acc[i][j]);
        }
        __syncthreads();
    }
    #pragma unroll
    for (int i = 0; i < 4; ++i) {
        int m = m0 + ty * 4 + i;
        #pragma unroll
        for (int j = 0; j < 4; ++j) {
            int n = n0 + tx * 4 + j;
            G[(size_t)m * N + n] = acc[i][j] + bias[n];
        }
    }
}

__global__ __launch_bounds__(256, 1) void lstm_recur(
    const float* __restrict__ Gf, const float* __restrict__ Gb,
    const float* __restrict__ Whf, const float* __restrict__ Whb,
    float* __restrict__ hist, float* __restrict__ h1buf,
    float* __restrict__ fin_h, float* __restrict__ fin_c,
    unsigned* __restrict__ flags, int layer)
{
    __shared__ float4 h4s[256];
    __shared__ float part[8 * 33];
    __shared__ float c_s[8];

    int tid = threadIdx.x;
    int cell = blockIdx.x >> 7;
    int gblk = blockIdx.x & 127;
    int j0 = gblk << 3;

    const float* Wh  = cell ? Whb : Whf;
    const float* Gin = cell ? Gb  : Gf;
    unsigned* myflags = flags + cell * 512;
    float* hout = (layer == 0) ? hist : h1buf;

    int tr = tid & 31, chunk = tid >> 5;
    int grow = ((tr >> 3) << 10) + j0 + (tr & 7);

    const float4* wrow = (const float4*)(Wh + (size_t)grow * 1024) + (chunk << 5);
    float4 w[32];
    #pragma unroll
    for (int i = 0; i < 32; ++i) w[i] = wrow[i];
    #pragma unroll
    for (int i = 0; i < 32; ++i)
        asm volatile("" : "+v"(w[i].x), "+v"(w[i].y), "+v"(w[i].z), "+v"(w[i].w));

    if (tid < 8) c_s[tid] = 0.f;

    for (int it = 0; it < SEQ; ++it) {
        int t = cell ? (SEQ - 1 - it) : it;
        float gpre = 0.f;
        if (tid < 32) gpre = Gin[(size_t)t * 4096 + grow];

        if (it == 0) {
            h4s[tid] = make_float4(0.f, 0.f, 0.f, 0.f);
        } else {
            if (tid < 64) {
                const unsigned* f0 = myflags + tid * 4;
                const unsigned* f1 = myflags + 256 + tid * 4;
                unsigned tgt = (unsigned)it;
                for (;;) {
                    unsigned a = LDA(f0);
                    unsigned b = LDA(f1);
                    if (__all(a >= tgt && b >= tgt)) break;
                    __builtin_amdgcn_s_sleep(1);
                }
            }
            __syncthreads();
            const float* hp;
            if (layer == 0)
                hp = cell ? (hist + (size_t)(t + 1) * 2048 + 1024)
                          : (hist + (size_t)(t - 1) * 2048);
            else
                hp = cell ? (h1buf + (size_t)(t + 1) * 2048 + 1024)
                          : (h1buf + (size_t)(t - 1) * 2048);
            const unsigned long long* hp64 = (const unsigned long long*)hp;
            unsigned long long u0, u1;
            for (;;) {
                u0 = LDA(hp64 + 2 * tid);
                u1 = LDA(hp64 + 2 * tid + 1);
                if (!(has_can(u0) | has_can(u1))) break;
            }
            h4s[tid] = make_float4(__uint_as_float((unsigned)u0),
                                   __uint_as_float((unsigned)(u0 >> 32)),
                                   __uint_as_float((unsigned)u1),
                                   __uint_as_float((unsigned)(u1 >> 32)));
        }
        __syncthreads();

        float a0 = 0.f, a1 = 0.f, a2 = 0.f, a3 = 0.f;
        const float4* hc = (const float4*)h4s + (chunk << 5);
        #pragma unroll
        for (int i = 0; i < 32; i += 4) {
            float4 h0 = hc[i], h1 = hc[i + 1], h2 = hc[i + 2], h3 = hc[i + 3];
            a0 = fmaf(w[i].x, h0.x, a0);     a0 = fmaf(w[i].y, h0.y, a0);
            a0 = fmaf(w[i].z, h0.z, a0);     a0 = fmaf(w[i].w, h0.w, a0);
            a1 = fmaf(w[i+1].x, h1.x, a1);   a1 = fmaf(w[i+1].y, h1.y, a1);
            a1 = fmaf(w[i+1].z, h1.z, a1);   a1 = fmaf(w[i+1].w, h1.w, a1);
            a2 = fmaf(w[i+2].x, h2.x, a2);   a2 = fmaf(w[i+2].y, h2.y, a2);
            a2 = fmaf(w[i+2].z, h2.z, a2);   a2 = fmaf(w[i+2].w, h2.w, a2);
            a3 = fmaf(w[i+3].x, h3.x, a3);   a3 = fmaf(w[i+3].y, h3.y, a3);
            a3 = fmaf(w[i+3].z, h3.z, a3);   a3 = fmaf(w[i+3].w, h3.w, a3);
        }
        part[chunk * 33 + tr] = (a0 + a1) + (a2 + a3);
        __syncthreads();

        if (tid < 32) {
            float v = gpre;
            #pragma unroll
            for (int k = 0; k < 8; ++k) v += part[k * 33 + tid];
            bool isg = (tid >> 3) == 2;
            float s = isg ? 2.f : 1.f;
            float e = __expf(-s * v);
            float r = 1.f / (1.f + e);
            float a = isg ? 2.f * r - 1.f : r;
            float si = __shfl(a, (tid & 7) + 0);
            float sf = __shfl(a, (tid & 7) + 8);
            float tg = __shfl(a, (tid & 7) + 16);
            float so = __shfl(a, (tid & 7) + 24);
            if (tid < 8) {
                float cnew = sf * c_s[tid] + si * tg;
                float e2 = __expf(-2.f * cnew);
                float hnew = so * (2.f / (1.f + e2) - 1.f);
                c_s[tid] = cnew;
                int j = j0 + tid;
                STA(&hout[(size_t)t * 2048 + cell * 1024 + j], hnew);
                if (it == SEQ - 1) {
                    STA(&fin_h[cell * 1024 + j], hnew);
                    STA(&fin_c[cell * 1024 + j], cnew);
                }
            }
            if (tid == 0 && it < SEQ - 1)
                STA(&myflags[gblk * 4], (unsigned)(it + 1));
        }
    }
}

// ---------------- launch ----------------
extern "C" void kernel_launch(void* const* d_in, const int* in_sizes, int n_in,
                              void* d_out, int out_size, void* d_ws, size_t ws_size,
                              hipStream_t stream) {
    const float* x      = (const float*)d_in[0];
    const float* w_ih0f = (const float*)d_in[1];
    const float* w_hh0f = (const float*)d_in[2];
    const float* b0f    = (const float*)d_in[3];
    const float* w_ih0b = (const float*)d_in[4];
    const float* w_hh0b = (const float*)d_in[5];
    const float* b0b    = (const float*)d_in[6];
    const float* w_ih1f = (const float*)d_in[7];
    const float* w_hh1f = (const float*)d_in[8];
    const float* b1f    = (const float*)d_in[9];
    const float* w_ih1b = (const float*)d_in[10];
    const float* w_hh1b = (const float*)d_in[11];
    const float* b1b    = (const float*)d_in[12];

    float* out   = (float*)d_out;
    float* outs0 = out + 8192;                 // [512,2048] == hist
    float* ws    = (float*)d_ws;
    float* G0f   = ws;                         // [512,4096]; G1f aliases after gate
    float* G0b   = ws + (size_t)512 * 4096;
    float* h1buf = ws + (size_t)2 * 512 * 4096;               // [512][2048]
    unsigned* flagbase = (unsigned*)(h1buf + (size_t)512 * 2048);
    unsigned* flags0 = flagbase;          // 1024 words
    unsigned* flags1 = flagbase + 1024;   // 1024 words
    unsigned* g0cnt  = flagbase + 2048;   // 16 chunk counters (cell*8+rc)
    unsigned* g1cnt  = flagbase + 2064;   // 16

    hipLaunchKernelGGL(init_bufs, dim3(1024), dim3(256), 0, stream,
                       flagbase, (unsigned*)outs0, (unsigned*)h1buf);

    int occ = 0;
    hipOccupancyMaxActiveBlocksPerMultiprocessor(&occ, lstm_fused, 256, 0);

    if (occ >= 2) {
        // fused pipeline: one cooperative kernel, 512 blocks (2/CU)
        const float* xp = x;
        const float* a1 = w_ih0f; const float* a2 = w_hh0f; const float* a3 = b0f;
        const float* a4 = w_ih0b; const float* a5 = w_hh0b; const float* a6 = b0b;
        const float* a7 = w_ih1f; const float* a8 = w_hh1f; const float* a9 = b1f;
        const float* aa = w_ih1b; const float* ab = w_hh1b; const float* ac = b1b;
        float* g0fp = G0f; float* g0bp = G0b;
        float* histp = outs0; float* h1p = h1buf; float* outp = out;
        unsigned* f0p = flags0; unsigned* f1p = flags1;
        unsigned* c0p = g0cnt;  unsigned* c1p = g1cnt;
        void* args[] = {(void*)&xp,
                        (void*)&a1, (void*)&a2, (void*)&a3,
                        (void*)&a4, (void*)&a5, (void*)&a6,
                        (void*)&a7, (void*)&a8, (void*)&a9,
                        (void*)&aa, (void*)&ab, (void*)&ac,
                        (void*)&g0fp, (void*)&g0bp,
                        (void*)&histp, (void*)&h1p, (void*)&outp,
                        (void*)&f0p, (void*)&f1p, (void*)&c0p, (void*)&c1p};
        hipLaunchCooperativeKernel((void*)lstm_fused, dim3(NRECUR + NGEMM),
                                   dim3(256), args, 0, stream);
    } else {
        // fallback: proven serial 4-kernel pipeline
        float* G1f = ws;
        float* G1b = ws + (size_t)512 * 4096;
        dim3 gb(64, 8, 2), tb(256);
        hipLaunchKernelGGL(gemm_bias2, gb, tb, 0, stream,
                           x, w_ih0f, w_ih0b, b0f, b0b, G0f, G0b, 512, 4096, 1024);
        {
            int layer = 0;
            const float* Gfp = G0f; const float* Gbp = G0b;
            const float* Whf = w_hh0f; const float* Whb = w_hh0b;
            float* hist = outs0; float* h1 = h1buf;
            float* finh = out;
            float* finc = out + 4096;
            unsigned* fl = flags0;
            void* args[] = {(void*)&Gfp, (void*)&Gbp, (void*)&Whf, (void*)&Whb,
                            (void*)&hist, (void*)&h1, (void*)&finh, (void*)&finc,
                            (void*)&fl, (void*)&layer};
            hipLaunchCooperativeKernel((void*)lstm_recur, dim3(256), dim3(256), args, 0, stream);
        }
        hipLaunchKernelGGL(gemm_bias2, gb, tb, 0, stream,
                           outs0, w_ih1f, w_ih1b, b1f, b1b, G1f, G1b, 512, 4096, 2048);
        {
            int layer = 1;
            const float* Gfp = G1f; const float* Gbp = G1b;
            const float* Whf = w_hh1f; const float* Whb = w_hh1b;
            float* hist = outs0; float* h1 = h1buf;
            float* finh = out + 2048;
            float* finc = out + 4096 + 2048;
            unsigned* fl = flags1;
            void* args[] = {(void*)&Gfp, (void*)&Gbp, (void*)&Whf, (void*)&Whb,
                            (void*)&hist, (void*)&h1, (void*)&finh, (void*)&finc,
                            (void*)&fl, (void*)&layer};
            hipLaunchCooperativeKernel((void*)lstm_recur, dim3(256), dim3(256), args, 0, stream);
        }
    }
}

// Round 4
// 2487.171 us; speedup vs baseline: 1.0707x; 1.0707x over previous
//
#include <hip/hip_runtime.h>

#define SEQ 512
#define CAN 0x7FC0DEADu   // qNaN payload canary: never produced by finite LSTM math
#define NRECUR 256
#define NGEMM  256
#define CNT_FULL 16384u   // 64 tiles/chunk * 256 threads: per-thread RELEASE adds

#define LDA(p)   __hip_atomic_load((p), __ATOMIC_RELAXED, __HIP_MEMORY_SCOPE_AGENT)
#define STA(p,v) __hip_atomic_store((p), (v), __ATOMIC_RELAXED, __HIP_MEMORY_SCOPE_AGENT)

__device__ __forceinline__ bool has_can(unsigned long long v) {
    return ((unsigned)v == CAN) | ((unsigned)(v >> 32) == CAN);
}

// zero flags+chunk counters, canary-fill both per-step h handoff buffers
__global__ __launch_bounds__(256) void init_bufs(
    unsigned* __restrict__ flags, unsigned* __restrict__ hist_u,
    unsigned* __restrict__ h1_u)
{
    int i = blockIdx.x * 256 + threadIdx.x;
    if (i < 2080) flags[i] = 0u;   // flags0[1024] flags1[1024] g0cnt[16] g1cnt[16]
    int stride = gridDim.x * 256;
    for (int k = i; k < 512 * 2048; k += stride) {
        hist_u[k] = CAN;
        h1_u[k]   = CAN;
    }
}

// ---------------- GEMM tile: G[64,64] = X[64,K] @ W[64,K]^T + bias ----------
// R3: LDS-vectorized fragments. Old loop read a[4],b[4] as 8x ds_read_b32 per
// thread per k (plus conflicts: 8.8e7 conflict cycles/dispatch) -- the GEMM's
// LDS storm queued the co-resident recurrence block's critical-path LDS ops
// behind it (LDS has no wave-priority arbitration), stalling the flag chain
// and nullifying the overlap. Rows padded to 68 floats (272B, 16B-aligned)
// so fragments load as 2x ds_read_b128; a-reads broadcast within 16-lane
// groups, b-reads hit 16 distinct 16B slots -> near conflict-free, 4x fewer
// LDS ops.
// XATOMIC: X is being produced by the recurrence in this same kernel -> read
// via agent-scope (LLC) loads with canary retry (flags are fire-and-forget,
// data may trail the flag). W/bias are kernel inputs (cached plain loads).
// G stores are agent-scope; each thread then RELEASE-increments the chunk
// counter, so cnt==CNT_FULL proves every thread's stores reached LLC.
template<bool XATOMIC>
__device__ void gemm_tile(const float* __restrict__ X, const float* __restrict__ W,
                          const float* __restrict__ bias, float* __restrict__ G,
                          int m0, int n0, int K,
                          float (*__restrict__ Xs)[68], float (*__restrict__ Ws)[68])
{
    int tid = threadIdx.x;
    int tx = tid & 15, ty = tid >> 4;
    int row = tid >> 2, kq = (tid & 3) << 2;
    float acc[4][4] = {};
    for (int k0 = 0; k0 < K; k0 += 16) {
        float4 vx;
        if (XATOMIC) {
            const unsigned long long* xp =
                (const unsigned long long*)(X + (size_t)(m0 + row) * K + k0 + kq);
            unsigned long long u0, u1;
            for (;;) {
                u0 = LDA(xp); u1 = LDA(xp + 1);
                if (!(has_can(u0) | has_can(u1))) break;
            }
            vx.x = __uint_as_float((unsigned)u0);
            vx.y = __uint_as_float((unsigned)(u0 >> 32));
            vx.z = __uint_as_float((unsigned)u1);
            vx.w = __uint_as_float((unsigned)(u1 >> 32));
        } else {
            vx = *(const float4*)(X + (size_t)(m0 + row) * K + k0 + kq);
        }
        Xs[kq + 0][row] = vx.x; Xs[kq + 1][row] = vx.y;
        Xs[kq + 2][row] = vx.z; Xs[kq + 3][row] = vx.w;
        float4 vw = *(const float4*)(W + (size_t)(n0 + row) * K + k0 + kq);
        Ws[kq + 0][row] = vw.x; Ws[kq + 1][row] = vw.y;
        Ws[kq + 2][row] = vw.z; Ws[kq + 3][row] = vw.w;
        __syncthreads();
        #pragma unroll
        for (int k = 0; k < 16; ++k) {
            float4 av = *(const float4*)&Xs[k][ty * 4];   // ds_read_b128
            float4 bv = *(const float4*)&Ws[k][tx * 4];   // ds_read_b128
            float a[4] = {av.x, av.y, av.z, av.w};
            float b[4] = {bv.x, bv.y, bv.z, bv.w};
            #pragma unroll
            for (int i = 0; i < 4; ++i)
                #pragma unroll
                for (int j = 0; j < 4; ++j)
                    acc[i][j] = fmaf(a[i], b[j], acc[i][j]);
        }
        __syncthreads();
    }
    #pragma unroll
    for (int i = 0; i < 4; ++i) {
        int m = m0 + ty * 4 + i;
        #pragma unroll
        for (int j = 0; j < 4; ++j) {
            int n = n0 + tx * 4 + j;
            STA(&G[(size_t)m * 4096 + n], acc[i][j] + bias[n]);
        }
    }
}

// wait until outs0 rows [64rc, 64rc+64) fully published AND consumed by
// recur-0: fwd flags >= 64rc+64, bwd flags >= 512-64rc. Long sleeps: slack.
__device__ void wait_outs0(const unsigned* __restrict__ flags0, int rc)
{
    unsigned tf = (unsigned)(64 * rc + 64);
    unsigned tb = (unsigned)(512 - 64 * rc);
    int tid = threadIdx.x;
    if (tid < 64) {
        const unsigned* ff = flags0 + tid * 4;          // fwd gblk tid / tid+64
        const unsigned* fb = flags0 + 512 + tid * 4;    // bwd
        for (;;) {
            unsigned a0 = LDA(ff), a1 = LDA(ff + 256);
            unsigned b0 = LDA(fb), b1 = LDA(fb + 256);
            if (__all(a0 >= tf && a1 >= tf && b0 >= tb && b1 >= tb)) break;
            __builtin_amdgcn_s_sleep(64);
        }
    }
    __syncthreads();
}

// ---------------- Recurrence cell (proven protocol) -------------------------
// Per-chunk G gate (it&63==0; chunk index t>>6 constant across each 64-step
// span in both directions): 8 dependent checks per 512 steps. gpre is a
// fire-and-forget LLC load hidden under the h-flag poll.
__device__ void recur_cell(
    const float* __restrict__ Gin, const float* __restrict__ Wh,
    float* __restrict__ hio, float* __restrict__ finh, float* __restrict__ finc,
    unsigned* __restrict__ myflags, const unsigned* __restrict__ gcnt,
    int cell, int gblk, float4* __restrict__ h4s, float* __restrict__ part)
{
    int tid = threadIdx.x;
    int j0 = gblk << 3;
    int tr = tid & 31, chunk = tid >> 5;
    int grow = ((tr >> 3) << 10) + j0 + (tr & 7);   // gate row in [0,4096)

    // W_hh slice -> regs (one-time), pinned via opaque asm (R3/R4 lesson)
    const float4* wrow = (const float4*)(Wh + (size_t)grow * 1024) + (chunk << 5);
    float4 w[32];
    #pragma unroll
    for (int i = 0; i < 32; ++i) w[i] = wrow[i];
    #pragma unroll
    for (int i = 0; i < 32; ++i)
        asm volatile("" : "+v"(w[i].x), "+v"(w[i].y), "+v"(w[i].z), "+v"(w[i].w));

    float cprev = 0.f;

    for (int it = 0; it < SEQ; ++it) {
        int t = cell ? (SEQ - 1 - it) : it;

        // per-chunk G gate: 8 dependent checks per 512 steps (R1 lesson)
        if ((it & 63) == 0 && tid < 32) {
            const unsigned* cp = gcnt + (t >> 6);
            while (LDA(cp) < CNT_FULL) __builtin_amdgcn_s_sleep(8);
        }
        // fire-and-forget prefetch, hidden under the h poll
        float gpre = 0.f;
        if (tid < 32)
            gpre = __uint_as_float(LDA((const unsigned*)Gin + (size_t)t * 4096 + grow));

        if (it == 0) {
            h4s[tid] = make_float4(0.f, 0.f, 0.f, 0.f);
        } else {
            if (tid < 64) {   // wave0 polls all 128 flags (2 per lane)
                const unsigned* f0 = myflags + tid * 4;
                const unsigned* f1 = myflags + 256 + tid * 4;
                unsigned tgt = (unsigned)it;
                for (;;) {
                    unsigned a = LDA(f0);
                    unsigned b = LDA(f1);
                    if (__all(a >= tgt && b >= tgt)) break;
                    __builtin_amdgcn_s_sleep(1);
                }
            }
            __syncthreads();
            const float* hp = cell ? (hio + (size_t)(t + 1) * 2048 + 1024)
                                   : (hio + (size_t)(t - 1) * 2048);
            const unsigned long long* hp64 = (const unsigned long long*)hp;
            unsigned long long u0, u1;
            for (;;) {   // canary-validated bulk load (retry rare)
                u0 = LDA(hp64 + 2 * tid);
                u1 = LDA(hp64 + 2 * tid + 1);
                if (!(has_can(u0) | has_can(u1))) break;
            }
            h4s[tid] = make_float4(__uint_as_float((unsigned)u0),
                                   __uint_as_float((unsigned)(u0 >> 32)),
                                   __uint_as_float((unsigned)u1),
                                   __uint_as_float((unsigned)(u1 >> 32)));
        }
        __syncthreads();

        // matvec: row tr, cols [chunk*128, +128); 4 independent acc chains
        float a0 = 0.f, a1 = 0.f, a2 = 0.f, a3 = 0.f;
        const float4* hc = h4s + (chunk << 5);
        #pragma unroll
        for (int i = 0; i < 32; i += 4) {
            float4 h0 = hc[i], h1 = hc[i + 1], h2 = hc[i + 2], h3 = hc[i + 3];
            a0 = fmaf(w[i].x, h0.x, a0);     a0 = fmaf(w[i].y, h0.y, a0);
            a0 = fmaf(w[i].z, h0.z, a0);     a0 = fmaf(w[i].w, h0.w, a0);
            a1 = fmaf(w[i+1].x, h1.x, a1);   a1 = fmaf(w[i+1].y, h1.y, a1);
            a1 = fmaf(w[i+1].z, h1.z, a1);   a1 = fmaf(w[i+1].w, h1.w, a1);
            a2 = fmaf(w[i+2].x, h2.x, a2);   a2 = fmaf(w[i+2].y, h2.y, a2);
            a2 = fmaf(w[i+2].z, h2.z, a2);   a2 = fmaf(w[i+2].w, h2.w, a2);
            a3 = fmaf(w[i+3].x, h3.x, a3);   a3 = fmaf(w[i+3].y, h3.y, a3);
            a3 = fmaf(w[i+3].z, h3.z, a3);   a3 = fmaf(w[i+3].w, h3.w, a3);
        }
        part[chunk * 33 + tr] = (a0 + a1) + (a2 + a3);
        __syncthreads();

        if (tid < 32) {
            float v = gpre;
            #pragma unroll
            for (int k = 0; k < 8; ++k) v += part[k * 33 + tid];
            bool isg = (tid >> 3) == 2;           // gate g -> tanh
            float s = isg ? 2.f : 1.f;
            float e = __expf(-s * v);
            float r = 1.f / (1.f + e);
            float a = isg ? 2.f * r - 1.f : r;
            float si = __shfl(a, (tid & 7) + 0);
            float sf = __shfl(a, (tid & 7) + 8);
            float tg = __shfl(a, (tid & 7) + 16);
            float so = __shfl(a, (tid & 7) + 24);
            if (tid < 8) {
                float cnew = sf * cprev + si * tg;
                float e2 = __expf(-2.f * cnew);
                float hnew = so * (2.f / (1.f + e2) - 1.f);
                cprev = cnew;
                int j = j0 + tid;
                STA(&hio[(size_t)t * 2048 + cell * 1024 + j], hnew);
                if (it == SEQ - 1) {
                    STA(&finh[j], hnew);
                    STA(&finc[j], cnew);
                }
            }
            if (tid == 0)   // every step incl. 511 (value 512): GEMM-1 gate
                STA(&myflags[gblk * 4], (unsigned)(it + 1));
        }
    }
}

// ---------------- Fused pipeline kernel -------------------------------------
// 512 cooperative blocks, 2/CU. Blocks [0,256): recurrence (layer0 then
// layer1, setprio 1). Blocks [256,512): GEMM workers streaming G0 then G1 in
// 64x64 tiles. G1 pair k = (fwd rc=k, bwd rc=7-k) becomes available at
// recur-0 step max(64k+64, 512-64k); korder lists pairs by availability so
// each worker's gated list is monotone -> middle chunks stream DURING recur0.
// G1 reuses G0's buffers: the readiness gate also proves the overwritten G0
// chunk was consumed.
__constant__ int korder[8] = {3, 4, 2, 5, 1, 6, 0, 7};

__global__ __launch_bounds__(256, 2) void lstm_fused(
    const float* __restrict__ x,
    const float* __restrict__ w_ih0f, const float* __restrict__ w_hh0f, const float* __restrict__ b0f,
    const float* __restrict__ w_ih0b, const float* __restrict__ w_hh0b, const float* __restrict__ b0b,
    const float* __restrict__ w_ih1f, const float* __restrict__ w_hh1f, const float* __restrict__ b1f,
    const float* __restrict__ w_ih1b, const float* __restrict__ w_hh1b, const float* __restrict__ b1b,
    float* __restrict__ G0f, float* __restrict__ G0b,
    float* __restrict__ hist, float* __restrict__ h1buf,
    float* __restrict__ out,
    unsigned* __restrict__ flags0, unsigned* __restrict__ flags1,
    unsigned* __restrict__ g0cnt, unsigned* __restrict__ g1cnt)
{
    __shared__ float4 h4s[256];
    __shared__ float part[8 * 33];
    __shared__ float Xs[16][68];
    __shared__ float Ws[16][68];

    int bid = blockIdx.x;
    if (bid < NRECUR) {
        __builtin_amdgcn_s_setprio(1);   // keep recurrence issue priority
        int cell = (bid >> 7) & 1;
        int gblk = bid & 127;
        recur_cell(cell ? G0b : G0f, cell ? w_hh0b : w_hh0f, hist,
                   out + cell * 1024, out + 4096 + cell * 1024,
                   flags0 + cell * 512, g0cnt + cell * 8, cell, gblk, h4s, part);
        recur_cell(cell ? G0b : G0f, cell ? w_hh1b : w_hh1f, h1buf,   // G1 aliases G0
                   out + 2048 + cell * 1024, out + 4096 + 2048 + cell * 1024,
                   flags1 + cell * 512, g1cnt + cell * 8, cell, gblk, h4s, part);
    } else {
        int gid = bid - NRECUR;
        // G0: no input gate (x is a kernel input); ends-first order
        for (int idx = gid; idx < 1024; idx += NGEMM) {
            int k = idx >> 7, half = (idx >> 6) & 1, cc = idx & 63;
            int rc = half ? (7 - k) : k;
            gemm_tile<false>(x, half ? w_ih0b : w_ih0f, half ? b0b : b0f,
                             half ? G0b : G0f, rc * 64, cc * 64, 1024, Xs, Ws);
            __hip_atomic_fetch_add(&g0cnt[half * 8 + rc], 1u,
                                   __ATOMIC_RELEASE, __HIP_MEMORY_SCOPE_AGENT);
        }
        // G1: gated on recur-0 progress; availability order (korder)
        for (int idx = gid; idx < 1024; idx += NGEMM) {
            int k = korder[idx >> 7], half = (idx >> 6) & 1, cc = idx & 63;
            int rc = half ? (7 - k) : k;
            wait_outs0(flags0, rc);
            gemm_tile<true>(hist, half ? w_ih1b : w_ih1f, half ? b1b : b1f,
                            half ? G0b : G0f, rc * 64, cc * 64, 2048, Xs, Ws);
            __hip_atomic_fetch_add(&g1cnt[half * 8 + rc], 1u,
                                   __ATOMIC_RELEASE, __HIP_MEMORY_SCOPE_AGENT);
        }
    }
}

// ================= Fallback path (proven 4-kernel version) ==================
__global__ __launch_bounds__(256) void gemm_bias2(
    const float* __restrict__ X,
    const float* __restrict__ Wf, const float* __restrict__ Wb,
    const float* __restrict__ biasf, const float* __restrict__ biasb,
    float* __restrict__ Gf, float* __restrict__ Gb,
    int M, int N, int K)
{
    const float* W    = blockIdx.z ? Wb : Wf;
    const float* bias = blockIdx.z ? biasb : biasf;
    float*       G    = blockIdx.z ? Gb : Gf;
    __shared__ float Xs[16][68];
    __shared__ float Ws[16][68];
    int tid = threadIdx.x;
    int tx = tid & 15, ty = tid >> 4;
    int m0 = blockIdx.y * 64, n0 = blockIdx.x * 64;
    float acc[4][4] = {};
    for (int k0 = 0; k0 < K; k0 += 16) {
        int row = tid >> 2, kq = (tid & 3) << 2;
        float4 vx = *(const float4*)(X + (size_t)(m0 + row) * K + k0 + kq);
        Xs[kq + 0][row] = vx.x; Xs[kq + 1][row] = vx.y;
        Xs[kq + 2][row] = vx.z; Xs[kq + 3][row] = vx.w;
        float4 vw = *(const float4*)(W + (size_t)(n0 + row) * K + k0 + kq);
        Ws[kq + 0][row] = vw.x; Ws[kq + 1][row] = vw.y;
        Ws[kq + 2][row] = vw.z; Ws[kq + 3][row] = vw.w;
        __syncthreads();
        #pragma unroll
        for (int k = 0; k < 16; ++k) {
            float4 av = *(const float4*)&Xs[k][ty * 4];
            float4 bv = *(const float4*)&Ws[k][tx * 4];
            float a[4] = {av.x, av.y, av.z, av.w};
            float b[4] = {bv.x, bv.y, bv.z, bv.w};
            #pragma unroll
            for (int i = 0; i < 4; ++i)
                #pragma unroll
                for (int j = 0; j < 4; ++j)
                    acc[i][j] = fmaf(a[i], b[j], acc[i][j]);
        }
        __syncthreads();
    }
    #pragma unroll
    for (int i = 0; i < 4; ++i) {
        int m = m0 + ty * 4 + i;
        #pragma unroll
        for (int j = 0; j < 4; ++j) {
            int n = n0 + tx * 4 + j;
            G[(size_t)m * N + n] = acc[i][j] + bias[n];
        }
    }
}

__global__ __launch_bounds__(256, 1) void lstm_recur(
    const float* __restrict__ Gf, const float* __restrict__ Gb,
    const float* __restrict__ Whf, const float* __restrict__ Whb,
    float* __restrict__ hist, float* __restrict__ h1buf,
    float* __restrict__ fin_h, float* __restrict__ fin_c,
    unsigned* __restrict__ flags, int layer)
{
    __shared__ float4 h4s[256];
    __shared__ float part[8 * 33];
    __shared__ float c_s[8];

    int tid = threadIdx.x;
    int cell = blockIdx.x >> 7;
    int gblk = blockIdx.x & 127;
    int j0 = gblk << 3;

    const float* Wh  = cell ? Whb : Whf;
    const float* Gin = cell ? Gb  : Gf;
    unsigned* myflags = flags + cell * 512;
    float* hout = (layer == 0) ? hist : h1buf;

    int tr = tid & 31, chunk = tid >> 5;
    int grow = ((tr >> 3) << 10) + j0 + (tr & 7);

    const float4* wrow = (const float4*)(Wh + (size_t)grow * 1024) + (chunk << 5);
    float4 w[32];
    #pragma unroll
    for (int i = 0; i < 32; ++i) w[i] = wrow[i];
    #pragma unroll
    for (int i = 0; i < 32; ++i)
        asm volatile("" : "+v"(w[i].x), "+v"(w[i].y), "+v"(w[i].z), "+v"(w[i].w));

    if (tid < 8) c_s[tid] = 0.f;

    for (int it = 0; it < SEQ; ++it) {
        int t = cell ? (SEQ - 1 - it) : it;
        float gpre = 0.f;
        if (tid < 32) gpre = Gin[(size_t)t * 4096 + grow];

        if (it == 0) {
            h4s[tid] = make_float4(0.f, 0.f, 0.f, 0.f);
        } else {
            if (tid < 64) {
                const unsigned* f0 = myflags + tid * 4;
                const unsigned* f1 = myflags + 256 + tid * 4;
                unsigned tgt = (unsigned)it;
                for (;;) {
                    unsigned a = LDA(f0);
                    unsigned b = LDA(f1);
                    if (__all(a >= tgt && b >= tgt)) break;
                    __builtin_amdgcn_s_sleep(1);
                }
            }
            __syncthreads();
            const float* hp;
            if (layer == 0)
                hp = cell ? (hist + (size_t)(t + 1) * 2048 + 1024)
                          : (hist + (size_t)(t - 1) * 2048);
            else
                hp = cell ? (h1buf + (size_t)(t + 1) * 2048 + 1024)
                          : (h1buf + (size_t)(t - 1) * 2048);
            const unsigned long long* hp64 = (const unsigned long long*)hp;
            unsigned long long u0, u1;
            for (;;) {
                u0 = LDA(hp64 + 2 * tid);
                u1 = LDA(hp64 + 2 * tid + 1);
                if (!(has_can(u0) | has_can(u1))) break;
            }
            h4s[tid] = make_float4(__uint_as_float((unsigned)u0),
                                   __uint_as_float((unsigned)(u0 >> 32)),
                                   __uint_as_float((unsigned)u1),
                                   __uint_as_float((unsigned)(u1 >> 32)));
        }
        __syncthreads();

        float a0 = 0.f, a1 = 0.f, a2 = 0.f, a3 = 0.f;
        const float4* hc = (const float4*)h4s + (chunk << 5);
        #pragma unroll
        for (int i = 0; i < 32; i += 4) {
            float4 h0 = hc[i], h1 = hc[i + 1], h2 = hc[i + 2], h3 = hc[i + 3];
            a0 = fmaf(w[i].x, h0.x, a0);     a0 = fmaf(w[i].y, h0.y, a0);
            a0 = fmaf(w[i].z, h0.z, a0);     a0 = fmaf(w[i].w, h0.w, a0);
            a1 = fmaf(w[i+1].x, h1.x, a1);   a1 = fmaf(w[i+1].y, h1.y, a1);
            a1 = fmaf(w[i+1].z, h1.z, a1);   a1 = fmaf(w[i+1].w, h1.w, a1);
            a2 = fmaf(w[i+2].x, h2.x, a2);   a2 = fmaf(w[i+2].y, h2.y, a2);
            a2 = fmaf(w[i+2].z, h2.z, a2);   a2 = fmaf(w[i+2].w, h2.w, a2);
            a3 = fmaf(w[i+3].x, h3.x, a3);   a3 = fmaf(w[i+3].y, h3.y, a3);
            a3 = fmaf(w[i+3].z, h3.z, a3);   a3 = fmaf(w[i+3].w, h3.w, a3);
        }
        part[chunk * 33 + tr] = (a0 + a1) + (a2 + a3);
        __syncthreads();

        if (tid < 32) {
            float v = gpre;
            #pragma unroll
            for (int k = 0; k < 8; ++k) v += part[k * 33 + tid];
            bool isg = (tid >> 3) == 2;
            float s = isg ? 2.f : 1.f;
            float e = __expf(-s * v);
            float r = 1.f / (1.f + e);
            float a = isg ? 2.f * r - 1.f : r;
            float si = __shfl(a, (tid & 7) + 0);
            float sf = __shfl(a, (tid & 7) + 8);
            float tg = __shfl(a, (tid & 7) + 16);
            float so = __shfl(a, (tid & 7) + 24);
            if (tid < 8) {
                float cnew = sf * c_s[tid] + si * tg;
                float e2 = __expf(-2.f * cnew);
                float hnew = so * (2.f / (1.f + e2) - 1.f);
                c_s[tid] = cnew;
                int j = j0 + tid;
                STA(&hout[(size_t)t * 2048 + cell * 1024 + j], hnew);
                if (it == SEQ - 1) {
                    STA(&fin_h[cell * 1024 + j], hnew);
                    STA(&fin_c[cell * 1024 + j], cnew);
                }
            }
            if (tid == 0 && it < SEQ - 1)
                STA(&myflags[gblk * 4], (unsigned)(it + 1));
        }
    }
}

// ---------------- launch ----------------
extern "C" void kernel_launch(void* const* d_in, const int* in_sizes, int n_in,
                              void* d_out, int out_size, void* d_ws, size_t ws_size,
                              hipStream_t stream) {
    const float* x      = (const float*)d_in[0];
    const float* w_ih0f = (const float*)d_in[1];
    const float* w_hh0f = (const float*)d_in[2];
    const float* b0f    = (const float*)d_in[3];
    const float* w_ih0b = (const float*)d_in[4];
    const float* w_hh0b = (const float*)d_in[5];
    const float* b0b    = (const float*)d_in[6];
    const float* w_ih1f = (const float*)d_in[7];
    const float* w_hh1f = (const float*)d_in[8];
    const float* b1f    = (const float*)d_in[9];
    const float* w_ih1b = (const float*)d_in[10];
    const float* w_hh1b = (const float*)d_in[11];
    const float* b1b    = (const float*)d_in[12];

    float* out   = (float*)d_out;
    float* outs0 = out + 8192;                 // [512,2048] == hist
    float* ws    = (float*)d_ws;
    float* G0f   = ws;                         // [512,4096]; G1f aliases after gate
    float* G0b   = ws + (size_t)512 * 4096;
    float* h1buf = ws + (size_t)2 * 512 * 4096;               // [512][2048]
    unsigned* flagbase = (unsigned*)(h1buf + (size_t)512 * 2048);
    unsigned* flags0 = flagbase;          // 1024 words
    unsigned* flags1 = flagbase + 1024;   // 1024 words
    unsigned* g0cnt  = flagbase + 2048;   // 16 chunk counters (cell*8+rc)
    unsigned* g1cnt  = flagbase + 2064;   // 16

    hipLaunchKernelGGL(init_bufs, dim3(1024), dim3(256), 0, stream,
                       flagbase, (unsigned*)outs0, (unsigned*)h1buf);

    int occ = 0;
    hipOccupancyMaxActiveBlocksPerMultiprocessor(&occ, lstm_fused, 256, 0);

    hipError_t lerr = hipErrorUnknown;
    if (occ >= 2) {
        // fused pipeline: one cooperative kernel, 512 blocks (2/CU)
        const float* xp = x;
        const float* a1 = w_ih0f; const float* a2 = w_hh0f; const float* a3 = b0f;
        const float* a4 = w_ih0b; const float* a5 = w_hh0b; const float* a6 = b0b;
        const float* a7 = w_ih1f; const float* a8 = w_hh1f; const float* a9 = b1f;
        const float* aa = w_ih1b; const float* ab = w_hh1b; const float* ac = b1b;
        float* g0fp = G0f; float* g0bp = G0b;
        float* histp = outs0; float* h1p = h1buf; float* outp = out;
        unsigned* f0p = flags0; unsigned* f1p = flags1;
        unsigned* c0p = g0cnt;  unsigned* c1p = g1cnt;
        void* args[] = {(void*)&xp,
                        (void*)&a1, (void*)&a2, (void*)&a3,
                        (void*)&a4, (void*)&a5, (void*)&a6,
                        (void*)&a7, (void*)&a8, (void*)&a9,
                        (void*)&aa, (void*)&ab, (void*)&ac,
                        (void*)&g0fp, (void*)&g0bp,
                        (void*)&histp, (void*)&h1p, (void*)&outp,
                        (void*)&f0p, (void*)&f1p, (void*)&c0p, (void*)&c1p};
        lerr = hipLaunchCooperativeKernel((void*)lstm_fused, dim3(NRECUR + NGEMM),
                                          dim3(256), args, 0, stream);
    }
    if (occ < 2 || lerr != hipSuccess) {
        // fallback: proven serial 4-kernel pipeline
        float* G1f = ws;
        float* G1b = ws + (size_t)512 * 4096;
        dim3 gb(64, 8, 2), tb(256);
        hipLaunchKernelGGL(gemm_bias2, gb, tb, 0, stream,
                           x, w_ih0f, w_ih0b, b0f, b0b, G0f, G0b, 512, 4096, 1024);
        {
            int layer = 0;
            const float* Gfp = G0f; const float* Gbp = G0b;
            const float* Whf = w_hh0f; const float* Whb = w_hh0b;
            float* hist = outs0; float* h1 = h1buf;
            float* finh = out;
            float* finc = out + 4096;
            unsigned* fl = flags0;
            void* args[] = {(void*)&Gfp, (void*)&Gbp, (void*)&Whf, (void*)&Whb,
                            (void*)&hist, (void*)&h1, (void*)&finh, (void*)&finc,
                            (void*)&fl, (void*)&layer};
            hipLaunchCooperativeKernel((void*)lstm_recur, dim3(256), dim3(256), args, 0, stream);
        }
        hipLaunchKernelGGL(gemm_bias2, gb, tb, 0, stream,
                           outs0, w_ih1f, w_ih1b, b1f, b1b, G1f, G1b, 512, 4096, 2048);
        {
            int layer = 1;
            const float* Gfp = G1f; const float* Gbp = G1b;
            const float* Whf = w_hh1f; const float* Whb = w_hh1b;
            float* hist = outs0; float* h1 = h1buf;
            float* finh = out + 2048;
            float* finc = out + 4096 + 2048;
            unsigned* fl = flags1;
            void* args[] = {(void*)&Gfp, (void*)&Gbp, (void*)&Whf, (void*)&Whb,
                            (void*)&hist, (void*)&h1, (void*)&finh, (void*)&finc,
                            (void*)&fl, (void*)&layer};
            hipLaunchCooperativeKernel((void*)lstm_recur, dim3(256), dim3(256), args, 0, stream);
        }
    }
}

// Round 5
// 2481.633 us; speedup vs baseline: 1.0731x; 1.0022x over previous
//
#include <hip/hip_runtime.h>

#define SEQ 512
#define CAN 0x7FC0DEADu   // qNaN payload canary: never produced by finite LSTM math
#define NRECUR 256
#define NGEMM  256
#define CNT_FULL 16384u   // 64 tiles/chunk * 256 threads: per-thread RELEASE adds

#define LDA(p)   __hip_atomic_load((p), __ATOMIC_RELAXED, __HIP_MEMORY_SCOPE_AGENT)
#define STA(p,v) __hip_atomic_store((p), (v), __ATOMIC_RELAXED, __HIP_MEMORY_SCOPE_AGENT)

__device__ __forceinline__ bool has_can(unsigned long long v) {
    return ((unsigned)v == CAN) | ((unsigned)(v >> 32) == CAN);
}
__device__ __forceinline__ bool has_can4(float4 v) {
    return (__float_as_uint(v.x) == CAN) | (__float_as_uint(v.y) == CAN) |
           (__float_as_uint(v.z) == CAN) | (__float_as_uint(v.w) == CAN);
}

// zero flags+chunk counters, canary-fill both per-step h handoff buffers
__global__ __launch_bounds__(256) void init_bufs(
    unsigned* __restrict__ flags, unsigned* __restrict__ hist_u,
    unsigned* __restrict__ h1_u)
{
    int i = blockIdx.x * 256 + threadIdx.x;
    if (i < 2080) flags[i] = 0u;   // flags0[1024] flags1[1024] g0cnt[16] g1cnt[16]
    int stride = gridDim.x * 256;
    for (int k = i; k < 512 * 2048; k += stride) {
        hist_u[k] = CAN;
        h1_u[k]   = CAN;
    }
}

// ---------------- GEMM tile: G[64,64] = X[64,K] @ W[64,K]^T + bias ----------
// LDS: rows padded to 68 floats so fragments load as 2x ds_read_b128 (R3 fix:
// conflicts 8.8e7 -> 1.26e7, wall -176us).
// XATOMIC (G1): X rows are gated-final (wait_outs0) and never rewritten, so
// use PLAIN CACHED loads (XCD-L2 reuse; kills ~500MB of LLC-direct re-reads
// that taxed the recurrence's critical LLC RTTs). Safety net: a stale L2 line
// can only hold the canary fill (the only other write ever is the final
// value), so canary => LDA (LLC-direct) retry; non-canary => provably final.
// G stores: 8B agent-scope stores (2x fewer LLC write ops than per-float).
// Each thread then RELEASE-increments the chunk counter, so cnt==CNT_FULL
// proves every thread's stores reached LLC.
template<bool XATOMIC>
__device__ void gemm_tile(const float* __restrict__ X, const float* __restrict__ W,
                          const float* __restrict__ bias, float* __restrict__ G,
                          int m0, int n0, int K,
                          float (*__restrict__ Xs)[68], float (*__restrict__ Ws)[68])
{
    int tid = threadIdx.x;
    int tx = tid & 15, ty = tid >> 4;
    int row = tid >> 2, kq = (tid & 3) << 2;
    float acc[4][4] = {};
    for (int k0 = 0; k0 < K; k0 += 16) {
        float4 vx;
        if (XATOMIC) {
            const float4* xp4 = (const float4*)(X + (size_t)(m0 + row) * K + k0 + kq);
            vx = *xp4;                      // plain cached (post-gate: final data)
            if (has_can4(vx)) {             // stale-L2 net: retry via LLC
                const unsigned long long* xp = (const unsigned long long*)xp4;
                unsigned long long u0, u1;
                for (;;) {
                    u0 = LDA(xp); u1 = LDA(xp + 1);
                    if (!(has_can(u0) | has_can(u1))) break;
                }
                vx.x = __uint_as_float((unsigned)u0);
                vx.y = __uint_as_float((unsigned)(u0 >> 32));
                vx.z = __uint_as_float((unsigned)u1);
                vx.w = __uint_as_float((unsigned)(u1 >> 32));
            }
        } else {
            vx = *(const float4*)(X + (size_t)(m0 + row) * K + k0 + kq);
        }
        Xs[kq + 0][row] = vx.x; Xs[kq + 1][row] = vx.y;
        Xs[kq + 2][row] = vx.z; Xs[kq + 3][row] = vx.w;
        float4 vw = *(const float4*)(W + (size_t)(n0 + row) * K + k0 + kq);
        Ws[kq + 0][row] = vw.x; Ws[kq + 1][row] = vw.y;
        Ws[kq + 2][row] = vw.z; Ws[kq + 3][row] = vw.w;
        __syncthreads();
        #pragma unroll
        for (int k = 0; k < 16; ++k) {
            float4 av = *(const float4*)&Xs[k][ty * 4];   // ds_read_b128
            float4 bv = *(const float4*)&Ws[k][tx * 4];   // ds_read_b128
            float a[4] = {av.x, av.y, av.z, av.w};
            float b[4] = {bv.x, bv.y, bv.z, bv.w};
            #pragma unroll
            for (int i = 0; i < 4; ++i)
                #pragma unroll
                for (int j = 0; j < 4; ++j)
                    acc[i][j] = fmaf(a[i], b[j], acc[i][j]);
        }
        __syncthreads();
    }
    #pragma unroll
    for (int i = 0; i < 4; ++i) {
        int m = m0 + ty * 4 + i;
        int n = n0 + tx * 4;
        #pragma unroll
        for (int jp = 0; jp < 2; ++jp) {   // two 8B packed agent stores
            float lo = acc[i][jp * 2]     + bias[n + jp * 2];
            float hi = acc[i][jp * 2 + 1] + bias[n + jp * 2 + 1];
            unsigned long long pk = (unsigned long long)__float_as_uint(lo) |
                                    ((unsigned long long)__float_as_uint(hi) << 32);
            STA((unsigned long long*)&G[(size_t)m * 4096 + n + jp * 2], pk);
        }
    }
}

// wait until outs0 rows [64rc, 64rc+64) fully published AND consumed by
// recur-0: fwd flags >= 64rc+64, bwd flags >= 512-64rc. Long sleeps: slack.
__device__ void wait_outs0(const unsigned* __restrict__ flags0, int rc)
{
    unsigned tf = (unsigned)(64 * rc + 64);
    unsigned tb = (unsigned)(512 - 64 * rc);
    int tid = threadIdx.x;
    if (tid < 64) {
        const unsigned* ff = flags0 + tid * 4;          // fwd gblk tid / tid+64
        const unsigned* fb = flags0 + 512 + tid * 4;    // bwd
        for (;;) {
            unsigned a0 = LDA(ff), a1 = LDA(ff + 256);
            unsigned b0 = LDA(fb), b1 = LDA(fb + 256);
            if (__all(a0 >= tf && a1 >= tf && b0 >= tb && b1 >= tb)) break;
            __builtin_amdgcn_s_sleep(64);
        }
    }
    __syncthreads();
}

// ---------------- Recurrence cell (proven protocol) -------------------------
// Per-chunk G gate (it&63==0; chunk index t>>6 constant across each 64-step
// span in both directions): 8 dependent checks per 512 steps. gpre is a
// fire-and-forget LLC load hidden under the h-flag poll.
__device__ void recur_cell(
    const float* __restrict__ Gin, const float* __restrict__ Wh,
    float* __restrict__ hio, float* __restrict__ finh, float* __restrict__ finc,
    unsigned* __restrict__ myflags, const unsigned* __restrict__ gcnt,
    int cell, int gblk, float4* __restrict__ h4s, float* __restrict__ part)
{
    int tid = threadIdx.x;
    int j0 = gblk << 3;
    int tr = tid & 31, chunk = tid >> 5;
    int grow = ((tr >> 3) << 10) + j0 + (tr & 7);   // gate row in [0,4096)

    // W_hh slice -> regs (one-time), pinned via opaque asm (R3/R4 lesson)
    const float4* wrow = (const float4*)(Wh + (size_t)grow * 1024) + (chunk << 5);
    float4 w[32];
    #pragma unroll
    for (int i = 0; i < 32; ++i) w[i] = wrow[i];
    #pragma unroll
    for (int i = 0; i < 32; ++i)
        asm volatile("" : "+v"(w[i].x), "+v"(w[i].y), "+v"(w[i].z), "+v"(w[i].w));

    float cprev = 0.f;

    for (int it = 0; it < SEQ; ++it) {
        int t = cell ? (SEQ - 1 - it) : it;

        // per-chunk G gate: 8 dependent checks per 512 steps (R1 lesson)
        if ((it & 63) == 0 && tid < 32) {
            const unsigned* cp = gcnt + (t >> 6);
            while (LDA(cp) < CNT_FULL) __builtin_amdgcn_s_sleep(8);
        }
        // fire-and-forget prefetch, hidden under the h poll
        float gpre = 0.f;
        if (tid < 32)
            gpre = __uint_as_float(LDA((const unsigned*)Gin + (size_t)t * 4096 + grow));

        if (it == 0) {
            h4s[tid] = make_float4(0.f, 0.f, 0.f, 0.f);
        } else {
            if (tid < 64) {   // wave0 polls all 128 flags (2 per lane)
                const unsigned* f0 = myflags + tid * 4;
                const unsigned* f1 = myflags + 256 + tid * 4;
                unsigned tgt = (unsigned)it;
                for (;;) {
                    unsigned a = LDA(f0);
                    unsigned b = LDA(f1);
                    if (__all(a >= tgt && b >= tgt)) break;
                    __builtin_amdgcn_s_sleep(1);
                }
            }
            __syncthreads();
            const float* hp = cell ? (hio + (size_t)(t + 1) * 2048 + 1024)
                                   : (hio + (size_t)(t - 1) * 2048);
            const unsigned long long* hp64 = (const unsigned long long*)hp;
            unsigned long long u0, u1;
            for (;;) {   // canary-validated bulk load (retry rare)
                u0 = LDA(hp64 + 2 * tid);
                u1 = LDA(hp64 + 2 * tid + 1);
                if (!(has_can(u0) | has_can(u1))) break;
            }
            h4s[tid] = make_float4(__uint_as_float((unsigned)u0),
                                   __uint_as_float((unsigned)(u0 >> 32)),
                                   __uint_as_float((unsigned)u1),
                                   __uint_as_float((unsigned)(u1 >> 32)));
        }
        __syncthreads();

        // matvec: row tr, cols [chunk*128, +128); 4 independent acc chains
        float a0 = 0.f, a1 = 0.f, a2 = 0.f, a3 = 0.f;
        const float4* hc = h4s + (chunk << 5);
        #pragma unroll
        for (int i = 0; i < 32; i += 4) {
            float4 h0 = hc[i], h1 = hc[i + 1], h2 = hc[i + 2], h3 = hc[i + 3];
            a0 = fmaf(w[i].x, h0.x, a0);     a0 = fmaf(w[i].y, h0.y, a0);
            a0 = fmaf(w[i].z, h0.z, a0);     a0 = fmaf(w[i].w, h0.w, a0);
            a1 = fmaf(w[i+1].x, h1.x, a1);   a1 = fmaf(w[i+1].y, h1.y, a1);
            a1 = fmaf(w[i+1].z, h1.z, a1);   a1 = fmaf(w[i+1].w, h1.w, a1);
            a2 = fmaf(w[i+2].x, h2.x, a2);   a2 = fmaf(w[i+2].y, h2.y, a2);
            a2 = fmaf(w[i+2].z, h2.z, a2);   a2 = fmaf(w[i+2].w, h2.w, a2);
            a3 = fmaf(w[i+3].x, h3.x, a3);   a3 = fmaf(w[i+3].y, h3.y, a3);
            a3 = fmaf(w[i+3].z, h3.z, a3);   a3 = fmaf(w[i+3].w, h3.w, a3);
        }
        part[chunk * 33 + tr] = (a0 + a1) + (a2 + a3);
        __syncthreads();

        if (tid < 32) {
            float v = gpre;
            #pragma unroll
            for (int k = 0; k < 8; ++k) v += part[k * 33 + tid];
            bool isg = (tid >> 3) == 2;           // gate g -> tanh
            float s = isg ? 2.f : 1.f;
            float e = __expf(-s * v);
            float r = 1.f / (1.f + e);
            float a = isg ? 2.f * r - 1.f : r;
            float si = __shfl(a, (tid & 7) + 0);
            float sf = __shfl(a, (tid & 7) + 8);
            float tg = __shfl(a, (tid & 7) + 16);
            float so = __shfl(a, (tid & 7) + 24);
            if (tid < 8) {
                float cnew = sf * cprev + si * tg;
                float e2 = __expf(-2.f * cnew);
                float hnew = so * (2.f / (1.f + e2) - 1.f);
                cprev = cnew;
                int j = j0 + tid;
                STA(&hio[(size_t)t * 2048 + cell * 1024 + j], hnew);
                if (it == SEQ - 1) {
                    STA(&finh[j], hnew);
                    STA(&finc[j], cnew);
                }
            }
            if (tid == 0)   // every step incl. 511 (value 512): GEMM-1 gate
                STA(&myflags[gblk * 4], (unsigned)(it + 1));
        }
    }
}

// ---------------- Fused pipeline kernel -------------------------------------
// 512 cooperative blocks, 2/CU. Blocks [0,256): recurrence (layer0 then
// layer1, setprio 1). Blocks [256,512): GEMM workers streaming G0 then G1 in
// 64x64 tiles. G1 pair k = (fwd rc=k, bwd rc=7-k) becomes available at
// recur-0 step max(64k+64, 512-64k); korder lists pairs by availability so
// each worker's gated list is monotone -> middle chunks stream DURING recur0.
// G1 reuses G0's buffers: the readiness gate also proves the overwritten G0
// chunk was consumed.
__constant__ int korder[8] = {3, 4, 2, 5, 1, 6, 0, 7};

__global__ __launch_bounds__(256, 2) void lstm_fused(
    const float* __restrict__ x,
    const float* __restrict__ w_ih0f, const float* __restrict__ w_hh0f, const float* __restrict__ b0f,
    const float* __restrict__ w_ih0b, const float* __restrict__ w_hh0b, const float* __restrict__ b0b,
    const float* __restrict__ w_ih1f, const float* __restrict__ w_hh1f, const float* __restrict__ b1f,
    const float* __restrict__ w_ih1b, const float* __restrict__ w_hh1b, const float* __restrict__ b1b,
    float* __restrict__ G0f, float* __restrict__ G0b,
    float* __restrict__ hist, float* __restrict__ h1buf,
    float* __restrict__ out,
    unsigned* __restrict__ flags0, unsigned* __restrict__ flags1,
    unsigned* __restrict__ g0cnt, unsigned* __restrict__ g1cnt)
{
    __shared__ float4 h4s[256];
    __shared__ float part[8 * 33];
    __shared__ float Xs[16][68];
    __shared__ float Ws[16][68];

    int bid = blockIdx.x;
    if (bid < NRECUR) {
        __builtin_amdgcn_s_setprio(1);   // keep recurrence issue priority
        int cell = (bid >> 7) & 1;
        int gblk = bid & 127;
        recur_cell(cell ? G0b : G0f, cell ? w_hh0b : w_hh0f, hist,
                   out + cell * 1024, out + 4096 + cell * 1024,
                   flags0 + cell * 512, g0cnt + cell * 8, cell, gblk, h4s, part);
        recur_cell(cell ? G0b : G0f, cell ? w_hh1b : w_hh1f, h1buf,   // G1 aliases G0
                   out + 2048 + cell * 1024, out + 4096 + 2048 + cell * 1024,
                   flags1 + cell * 512, g1cnt + cell * 8, cell, gblk, h4s, part);
    } else {
        int gid = bid - NRECUR;
        // G0: no input gate (x is a kernel input); ends-first order
        for (int idx = gid; idx < 1024; idx += NGEMM) {
            int k = idx >> 7, half = (idx >> 6) & 1, cc = idx & 63;
            int rc = half ? (7 - k) : k;
            gemm_tile<false>(x, half ? w_ih0b : w_ih0f, half ? b0b : b0f,
                             half ? G0b : G0f, rc * 64, cc * 64, 1024, Xs, Ws);
            __hip_atomic_fetch_add(&g0cnt[half * 8 + rc], 1u,
                                   __ATOMIC_RELEASE, __HIP_MEMORY_SCOPE_AGENT);
        }
        // G1: gated on recur-0 progress; availability order (korder)
        for (int idx = gid; idx < 1024; idx += NGEMM) {
            int k = korder[idx >> 7], half = (idx >> 6) & 1, cc = idx & 63;
            int rc = half ? (7 - k) : k;
            wait_outs0(flags0, rc);
            gemm_tile<true>(hist, half ? w_ih1b : w_ih1f, half ? b1b : b1f,
                            half ? G0b : G0f, rc * 64, cc * 64, 2048, Xs, Ws);
            __hip_atomic_fetch_add(&g1cnt[half * 8 + rc], 1u,
                                   __ATOMIC_RELEASE, __HIP_MEMORY_SCOPE_AGENT);
        }
    }
}

// ================= Fallback path (proven 4-kernel version) ==================
__global__ __launch_bounds__(256) void gemm_bias2(
    const float* __restrict__ X,
    const float* __restrict__ Wf, const float* __restrict__ Wb,
    const float* __restrict__ biasf, const float* __restrict__ biasb,
    float* __restrict__ Gf, float* __restrict__ Gb,
    int M, int N, int K)
{
    const float* W    = blockIdx.z ? Wb : Wf;
    const float* bias = blockIdx.z ? biasb : biasf;
    float*       G    = blockIdx.z ? Gb : Gf;
    __shared__ float Xs[16][68];
    __shared__ float Ws[16][68];
    int tid = threadIdx.x;
    int tx = tid & 15, ty = tid >> 4;
    int m0 = blockIdx.y * 64, n0 = blockIdx.x * 64;
    float acc[4][4] = {};
    for (int k0 = 0; k0 < K; k0 += 16) {
        int row = tid >> 2, kq = (tid & 3) << 2;
        float4 vx = *(const float4*)(X + (size_t)(m0 + row) * K + k0 + kq);
        Xs[kq + 0][row] = vx.x; Xs[kq + 1][row] = vx.y;
        Xs[kq + 2][row] = vx.z; Xs[kq + 3][row] = vx.w;
        float4 vw = *(const float4*)(W + (size_t)(n0 + row) * K + k0 + kq);
        Ws[kq + 0][row] = vw.x; Ws[kq + 1][row] = vw.y;
        Ws[kq + 2][row] = vw.z; Ws[kq + 3][row] = vw.w;
        __syncthreads();
        #pragma unroll
        for (int k = 0; k < 16; ++k) {
            float4 av = *(const float4*)&Xs[k][ty * 4];
            float4 bv = *(const float4*)&Ws[k][tx * 4];
            float a[4] = {av.x, av.y, av.z, av.w};
            float b[4] = {bv.x, bv.y, bv.z, bv.w};
            #pragma unroll
            for (int i = 0; i < 4; ++i)
                #pragma unroll
                for (int j = 0; j < 4; ++j)
                    acc[i][j] = fmaf(a[i], b[j], acc[i][j]);
        }
        __syncthreads();
    }
    #pragma unroll
    for (int i = 0; i < 4; ++i) {
        int m = m0 + ty * 4 + i;
        #pragma unroll
        for (int j = 0; j < 4; ++j) {
            int n = n0 + tx * 4 + j;
            G[(size_t)m * N + n] = acc[i][j] + bias[n];
        }
    }
}

__global__ __launch_bounds__(256, 1) void lstm_recur(
    const float* __restrict__ Gf, const float* __restrict__ Gb,
    const float* __restrict__ Whf, const float* __restrict__ Whb,
    float* __restrict__ hist, float* __restrict__ h1buf,
    float* __restrict__ fin_h, float* __restrict__ fin_c,
    unsigned* __restrict__ flags, int layer)
{
    __shared__ float4 h4s[256];
    __shared__ float part[8 * 33];
    __shared__ float c_s[8];

    int tid = threadIdx.x;
    int cell = blockIdx.x >> 7;
    int gblk = blockIdx.x & 127;
    int j0 = gblk << 3;

    const float* Wh  = cell ? Whb : Whf;
    const float* Gin = cell ? Gb  : Gf;
    unsigned* myflags = flags + cell * 512;
    float* hout = (layer == 0) ? hist : h1buf;

    int tr = tid & 31, chunk = tid >> 5;
    int grow = ((tr >> 3) << 10) + j0 + (tr & 7);

    const float4* wrow = (const float4*)(Wh + (size_t)grow * 1024) + (chunk << 5);
    float4 w[32];
    #pragma unroll
    for (int i = 0; i < 32; ++i) w[i] = wrow[i];
    #pragma unroll
    for (int i = 0; i < 32; ++i)
        asm volatile("" : "+v"(w[i].x), "+v"(w[i].y), "+v"(w[i].z), "+v"(w[i].w));

    if (tid < 8) c_s[tid] = 0.f;

    for (int it = 0; it < SEQ; ++it) {
        int t = cell ? (SEQ - 1 - it) : it;
        float gpre = 0.f;
        if (tid < 32) gpre = Gin[(size_t)t * 4096 + grow];

        if (it == 0) {
            h4s[tid] = make_float4(0.f, 0.f, 0.f, 0.f);
        } else {
            if (tid < 64) {
                const unsigned* f0 = myflags + tid * 4;
                const unsigned* f1 = myflags + 256 + tid * 4;
                unsigned tgt = (unsigned)it;
                for (;;) {
                    unsigned a = LDA(f0);
                    unsigned b = LDA(f1);
                    if (__all(a >= tgt && b >= tgt)) break;
                    __builtin_amdgcn_s_sleep(1);
                }
            }
            __syncthreads();
            const float* hp;
            if (layer == 0)
                hp = cell ? (hist + (size_t)(t + 1) * 2048 + 1024)
                          : (hist + (size_t)(t - 1) * 2048);
            else
                hp = cell ? (h1buf + (size_t)(t + 1) * 2048 + 1024)
                          : (h1buf + (size_t)(t - 1) * 2048);
            const unsigned long long* hp64 = (const unsigned long long*)hp;
            unsigned long long u0, u1;
            for (;;) {
                u0 = LDA(hp64 + 2 * tid);
                u1 = LDA(hp64 + 2 * tid + 1);
                if (!(has_can(u0) | has_can(u1))) break;
            }
            h4s[tid] = make_float4(__uint_as_float((unsigned)u0),
                                   __uint_as_float((unsigned)(u0 >> 32)),
                                   __uint_as_float((unsigned)u1),
                                   __uint_as_float((unsigned)(u1 >> 32)));
        }
        __syncthreads();

        float a0 = 0.f, a1 = 0.f, a2 = 0.f, a3 = 0.f;
        const float4* hc = (const float4*)h4s + (chunk << 5);
        #pragma unroll
        for (int i = 0; i < 32; i += 4) {
            float4 h0 = hc[i], h1 = hc[i + 1], h2 = hc[i + 2], h3 = hc[i + 3];
            a0 = fmaf(w[i].x, h0.x, a0);     a0 = fmaf(w[i].y, h0.y, a0);
            a0 = fmaf(w[i].z, h0.z, a0);     a0 = fmaf(w[i].w, h0.w, a0);
            a1 = fmaf(w[i+1].x, h1.x, a1);   a1 = fmaf(w[i+1].y, h1.y, a1);
            a1 = fmaf(w[i+1].z, h1.z, a1);   a1 = fmaf(w[i+1].w, h1.w, a1);
            a2 = fmaf(w[i+2].x, h2.x, a2);   a2 = fmaf(w[i+2].y, h2.y, a2);
            a2 = fmaf(w[i+2].z, h2.z, a2);   a2 = fmaf(w[i+2].w, h2.w, a2);
            a3 = fmaf(w[i+3].x, h3.x, a3);   a3 = fmaf(w[i+3].y, h3.y, a3);
            a3 = fmaf(w[i+3].z, h3.z, a3);   a3 = fmaf(w[i+3].w, h3.w, a3);
        }
        part[chunk * 33 + tr] = (a0 + a1) + (a2 + a3);
        __syncthreads();

        if (tid < 32) {
            float v = gpre;
            #pragma unroll
            for (int k = 0; k < 8; ++k) v += part[k * 33 + tid];
            bool isg = (tid >> 3) == 2;
            float s = isg ? 2.f : 1.f;
            float e = __expf(-s * v);
            float r = 1.f / (1.f + e);
            float a = isg ? 2.f * r - 1.f : r;
            float si = __shfl(a, (tid & 7) + 0);
            float sf = __shfl(a, (tid & 7) + 8);
            float tg = __shfl(a, (tid & 7) + 16);
            float so = __shfl(a, (tid & 7) + 24);
            if (tid < 8) {
                float cnew = sf * c_s[tid] + si * tg;
                float e2 = __expf(-2.f * cnew);
                float hnew = so * (2.f / (1.f + e2) - 1.f);
                c_s[tid] = cnew;
                int j = j0 + tid;
                STA(&hout[(size_t)t * 2048 + cell * 1024 + j], hnew);
                if (it == SEQ - 1) {
                    STA(&fin_h[cell * 1024 + j], hnew);
                    STA(&fin_c[cell * 1024 + j], cnew);
                }
            }
            if (tid == 0 && it < SEQ - 1)
                STA(&myflags[gblk * 4], (unsigned)(it + 1));
        }
    }
}

// ---------------- launch ----------------
extern "C" void kernel_launch(void* const* d_in, const int* in_sizes, int n_in,
                              void* d_out, int out_size, void* d_ws, size_t ws_size,
                              hipStream_t stream) {
    const float* x      = (const float*)d_in[0];
    const float* w_ih0f = (const float*)d_in[1];
    const float* w_hh0f = (const float*)d_in[2];
    const float* b0f    = (const float*)d_in[3];
    const float* w_ih0b = (const float*)d_in[4];
    const float* w_hh0b = (const float*)d_in[5];
    const float* b0b    = (const float*)d_in[6];
    const float* w_ih1f = (const float*)d_in[7];
    const float* w_hh1f = (const float*)d_in[8];
    const float* b1f    = (const float*)d_in[9];
    const float* w_ih1b = (const float*)d_in[10];
    const float* w_hh1b = (const float*)d_in[11];
    const float* b1b    = (const float*)d_in[12];

    float* out   = (float*)d_out;
    float* outs0 = out + 8192;                 // [512,2048] == hist
    float* ws    = (float*)d_ws;
    float* G0f   = ws;                         // [512,4096]; G1f aliases after gate
    float* G0b   = ws + (size_t)512 * 4096;
    float* h1buf = ws + (size_t)2 * 512 * 4096;               // [512][2048]
    unsigned* flagbase = (unsigned*)(h1buf + (size_t)512 * 2048);
    unsigned* flags0 = flagbase;          // 1024 words
    unsigned* flags1 = flagbase + 1024;   // 1024 words
    unsigned* g0cnt  = flagbase + 2048;   // 16 chunk counters (cell*8+rc)
    unsigned* g1cnt  = flagbase + 2064;   // 16

    hipLaunchKernelGGL(init_bufs, dim3(1024), dim3(256), 0, stream,
                       flagbase, (unsigned*)outs0, (unsigned*)h1buf);

    int occ = 0;
    hipOccupancyMaxActiveBlocksPerMultiprocessor(&occ, lstm_fused, 256, 0);

    hipError_t lerr = hipErrorUnknown;
    if (occ >= 2) {
        // fused pipeline: one cooperative kernel, 512 blocks (2/CU)
        const float* xp = x;
        const float* a1 = w_ih0f; const float* a2 = w_hh0f; const float* a3 = b0f;
        const float* a4 = w_ih0b; const float* a5 = w_hh0b; const float* a6 = b0b;
        const float* a7 = w_ih1f; const float* a8 = w_hh1f; const float* a9 = b1f;
        const float* aa = w_ih1b; const float* ab = w_hh1b; const float* ac = b1b;
        float* g0fp = G0f; float* g0bp = G0b;
        float* histp = outs0; float* h1p = h1buf; float* outp = out;
        unsigned* f0p = flags0; unsigned* f1p = flags1;
        unsigned* c0p = g0cnt;  unsigned* c1p = g1cnt;
        void* args[] = {(void*)&xp,
                        (void*)&a1, (void*)&a2, (void*)&a3,
                        (void*)&a4, (void*)&a5, (void*)&a6,
                        (void*)&a7, (void*)&a8, (void*)&a9,
                        (void*)&aa, (void*)&ab, (void*)&ac,
                        (void*)&g0fp, (void*)&g0bp,
                        (void*)&histp, (void*)&h1p, (void*)&outp,
                        (void*)&f0p, (void*)&f1p, (void*)&c0p, (void*)&c1p};
        lerr = hipLaunchCooperativeKernel((void*)lstm_fused, dim3(NRECUR + NGEMM),
                                          dim3(256), args, 0, stream);
    }
    if (occ < 2 || lerr != hipSuccess) {
        // fallback: proven serial 4-kernel pipeline
        float* G1f = ws;
        float* G1b = ws + (size_t)512 * 4096;
        dim3 gb(64, 8, 2), tb(256);
        hipLaunchKernelGGL(gemm_bias2, gb, tb, 0, stream,
                           x, w_ih0f, w_ih0b, b0f, b0b, G0f, G0b, 512, 4096, 1024);
        {
            int layer = 0;
            const float* Gfp = G0f; const float* Gbp = G0b;
            const float* Whf = w_hh0f; const float* Whb = w_hh0b;
            float* hist = outs0; float* h1 = h1buf;
            float* finh = out;
            float* finc = out + 4096;
            unsigned* fl = flags0;
            void* args[] = {(void*)&Gfp, (void*)&Gbp, (void*)&Whf, (void*)&Whb,
                            (void*)&hist, (void*)&h1, (void*)&finh, (void*)&finc,
                            (void*)&fl, (void*)&layer};
            hipLaunchCooperativeKernel((void*)lstm_recur, dim3(256), dim3(256), args, 0, stream);
        }
        hipLaunchKernelGGL(gemm_bias2, gb, tb, 0, stream,
                           outs0, w_ih1f, w_ih1b, b1f, b1b, G1f, G1b, 512, 4096, 2048);
        {
            int layer = 1;
            const float* Gfp = G1f; const float* Gbp = G1b;
            const float* Whf = w_hh1f; const float* Whb = w_hh1b;
            float* hist = outs0; float* h1 = h1buf;
            float* finh = out + 2048;
            float* finc = out + 4096 + 2048;
            unsigned* fl = flags1;
            void* args[] = {(void*)&Gfp, (void*)&Gbp, (void*)&Whf, (void*)&Whb,
                            (void*)&hist, (void*)&h1, (void*)&finh, (void*)&finc,
                            (void*)&fl, (void*)&layer};
            hipLaunchCooperativeKernel((void*)lstm_recur, dim3(256), dim3(256), args, 0, stream);
        }
    }
}

// Round 6
// 2480.289 us; speedup vs baseline: 1.0737x; 1.0005x over previous
//
#include <hip/hip_runtime.h>

#define SEQ 512
#define CAN 0x7FC0DEADu   // qNaN payload canary: never produced by finite LSTM math
#define NRECUR 256
#define NGEMM  256
#define CNT_FULL 16384u   // 64 tiles/chunk * 256 threads: per-thread RELEASE adds

#define LDA(p)   __hip_atomic_load((p), __ATOMIC_RELAXED, __HIP_MEMORY_SCOPE_AGENT)
#define STA(p,v) __hip_atomic_store((p), (v), __ATOMIC_RELAXED, __HIP_MEMORY_SCOPE_AGENT)

__device__ __forceinline__ bool has_can(unsigned long long v) {
    return ((unsigned)v == CAN) | ((unsigned)(v >> 32) == CAN);
}
__device__ __forceinline__ bool has_can4(float4 v) {
    return (__float_as_uint(v.x) == CAN) | (__float_as_uint(v.y) == CAN) |
           (__float_as_uint(v.z) == CAN) | (__float_as_uint(v.w) == CAN);
}

// zero flags+chunk counters, canary-fill both per-step h handoff buffers
__global__ __launch_bounds__(256) void init_bufs(
    unsigned* __restrict__ flags, unsigned* __restrict__ hist_u,
    unsigned* __restrict__ h1_u)
{
    int i = blockIdx.x * 256 + threadIdx.x;
    if (i < 2080) flags[i] = 0u;   // flags0[1024] flags1[1024] g0cnt[16] g1cnt[16]
    int stride = gridDim.x * 256;
    for (int k = i; k < 512 * 2048; k += stride) {
        hist_u[k] = CAN;
        h1_u[k]   = CAN;
    }
}

// ---------------- GEMM tile: G[64,64] = X[64,K] @ W[64,K]^T + bias ----------
// LDS: rows padded to 68 floats so fragments load as 2x ds_read_b128 (R3 fix:
// conflicts 8.8e7 -> 1.26e7, wall -176us).
// XATOMIC (G1): X rows are gated-final (wait_outs0) and never rewritten, so
// plain cached loads (XCD-L2 reuse); canary => LDA (LLC-direct) retry net.
// G stores: 8B agent-scope stores. Each thread RELEASE-increments the chunk
// counter, so cnt==CNT_FULL proves every thread's stores reached LLC.
template<bool XATOMIC>
__device__ void gemm_tile(const float* __restrict__ X, const float* __restrict__ W,
                          const float* __restrict__ bias, float* __restrict__ G,
                          int m0, int n0, int K,
                          float (*__restrict__ Xs)[68], float (*__restrict__ Ws)[68])
{
    int tid = threadIdx.x;
    int tx = tid & 15, ty = tid >> 4;
    int row = tid >> 2, kq = (tid & 3) << 2;
    float acc[4][4] = {};
    for (int k0 = 0; k0 < K; k0 += 16) {
        float4 vx;
        if (XATOMIC) {
            const float4* xp4 = (const float4*)(X + (size_t)(m0 + row) * K + k0 + kq);
            vx = *xp4;                      // plain cached (post-gate: final data)
            if (has_can4(vx)) {             // stale-L2 net: retry via LLC
                const unsigned long long* xp = (const unsigned long long*)xp4;
                unsigned long long u0, u1;
                for (;;) {
                    u0 = LDA(xp); u1 = LDA(xp + 1);
                    if (!(has_can(u0) | has_can(u1))) break;
                }
                vx.x = __uint_as_float((unsigned)u0);
                vx.y = __uint_as_float((unsigned)(u0 >> 32));
                vx.z = __uint_as_float((unsigned)u1);
                vx.w = __uint_as_float((unsigned)(u1 >> 32));
            }
        } else {
            vx = *(const float4*)(X + (size_t)(m0 + row) * K + k0 + kq);
        }
        Xs[kq + 0][row] = vx.x; Xs[kq + 1][row] = vx.y;
        Xs[kq + 2][row] = vx.z; Xs[kq + 3][row] = vx.w;
        float4 vw = *(const float4*)(W + (size_t)(n0 + row) * K + k0 + kq);
        Ws[kq + 0][row] = vw.x; Ws[kq + 1][row] = vw.y;
        Ws[kq + 2][row] = vw.z; Ws[kq + 3][row] = vw.w;
        __syncthreads();
        #pragma unroll
        for (int k = 0; k < 16; ++k) {
            float4 av = *(const float4*)&Xs[k][ty * 4];   // ds_read_b128
            float4 bv = *(const float4*)&Ws[k][tx * 4];   // ds_read_b128
            float a[4] = {av.x, av.y, av.z, av.w};
            float b[4] = {bv.x, bv.y, bv.z, bv.w};
            #pragma unroll
            for (int i = 0; i < 4; ++i)
                #pragma unroll
                for (int j = 0; j < 4; ++j)
                    acc[i][j] = fmaf(a[i], b[j], acc[i][j]);
        }
        __syncthreads();
    }
    #pragma unroll
    for (int i = 0; i < 4; ++i) {
        int m = m0 + ty * 4 + i;
        int n = n0 + tx * 4;
        #pragma unroll
        for (int jp = 0; jp < 2; ++jp) {   // two 8B packed agent stores
            float lo = acc[i][jp * 2]     + bias[n + jp * 2];
            float hi = acc[i][jp * 2 + 1] + bias[n + jp * 2 + 1];
            unsigned long long pk = (unsigned long long)__float_as_uint(lo) |
                                    ((unsigned long long)__float_as_uint(hi) << 32);
            STA((unsigned long long*)&G[(size_t)m * 4096 + n + jp * 2], pk);
        }
    }
}

// wait until outs0 rows [64rc, 64rc+64) fully published AND consumed by
// recur-0: fwd flags >= 64rc+64, bwd flags >= 512-64rc. Long sleeps: slack.
__device__ void wait_outs0(const unsigned* __restrict__ flags0, int rc)
{
    unsigned tf = (unsigned)(64 * rc + 64);
    unsigned tb = (unsigned)(512 - 64 * rc);
    int tid = threadIdx.x;
    if (tid < 64) {
        const unsigned* ff = flags0 + tid * 4;          // fwd gblk tid / tid+64
        const unsigned* fb = flags0 + 512 + tid * 4;    // bwd
        for (;;) {
            unsigned a0 = LDA(ff), a1 = LDA(ff + 256);
            unsigned b0 = LDA(fb), b1 = LDA(fb + 256);
            if (__all(a0 >= tf && a1 >= tf && b0 >= tb && b1 >= tb)) break;
            __builtin_amdgcn_s_sleep(64);
        }
    }
    __syncthreads();
}

// ---------------- Recurrence cell --------------------------------------------
// R5: DATA-DIRECT handoff. The old step chain had two serialized LLC RTTs:
// poll flags -> detect -> dependent h load (+canary check). The canary-retry
// IS a complete per-word synchronization (valid-or-canary), so the flag
// pre-gate is redundant on the consumer side: drop the poll, let every thread
// spin directly on its own 32B of h until canary-free. Removes one LLC RTT +
// s_sleep quantization per step, both layers. Flags are still STORED every
// step (wait_outs0 / GEMM-1 gating consumes them) -- just never polled here.
// Retry traffic: 8KB/block at load-latency period ~ 1.8 TB/s burst, fine
// (old "R5 lesson" was 256-thread flag hammering, different regime).
__device__ void recur_cell(
    const float* __restrict__ Gin, const float* __restrict__ Wh,
    float* __restrict__ hio, float* __restrict__ finh, float* __restrict__ finc,
    unsigned* __restrict__ myflags, const unsigned* __restrict__ gcnt,
    int cell, int gblk, float4* __restrict__ h4s, float* __restrict__ part)
{
    int tid = threadIdx.x;
    int j0 = gblk << 3;
    int tr = tid & 31, chunk = tid >> 5;
    int grow = ((tr >> 3) << 10) + j0 + (tr & 7);   // gate row in [0,4096)

    // W_hh slice -> regs (one-time), pinned via opaque asm (R3/R4 lesson)
    const float4* wrow = (const float4*)(Wh + (size_t)grow * 1024) + (chunk << 5);
    float4 w[32];
    #pragma unroll
    for (int i = 0; i < 32; ++i) w[i] = wrow[i];
    #pragma unroll
    for (int i = 0; i < 32; ++i)
        asm volatile("" : "+v"(w[i].x), "+v"(w[i].y), "+v"(w[i].z), "+v"(w[i].w));

    float cprev = 0.f;

    for (int it = 0; it < SEQ; ++it) {
        int t = cell ? (SEQ - 1 - it) : it;

        // per-chunk G gate: 8 dependent checks per 512 steps (R1 lesson)
        if ((it & 63) == 0 && tid < 32) {
            const unsigned* cp = gcnt + (t >> 6);
            while (LDA(cp) < CNT_FULL) __builtin_amdgcn_s_sleep(8);
        }
        // fire-and-forget prefetch, hidden under the h canary-wait
        float gpre = 0.f;
        if (tid < 32)
            gpre = __uint_as_float(LDA((const unsigned*)Gin + (size_t)t * 4096 + grow));

        if (it == 0) {
            h4s[tid] = make_float4(0.f, 0.f, 0.f, 0.f);
        } else {
            const float* hp = cell ? (hio + (size_t)(t + 1) * 2048 + 1024)
                                   : (hio + (size_t)(t - 1) * 2048);
            const unsigned long long* hp64 = (const unsigned long long*)hp;
            unsigned long long u0, u1;
            for (;;) {   // canary-validated load IS the wait (data-direct)
                u0 = LDA(hp64 + 2 * tid);
                u1 = LDA(hp64 + 2 * tid + 1);
                if (!(has_can(u0) | has_can(u1))) break;
            }
            h4s[tid] = make_float4(__uint_as_float((unsigned)u0),
                                   __uint_as_float((unsigned)(u0 >> 32)),
                                   __uint_as_float((unsigned)u1),
                                   __uint_as_float((unsigned)(u1 >> 32)));
        }
        __syncthreads();

        // matvec: row tr, cols [chunk*128, +128); 4 independent acc chains
        float a0 = 0.f, a1 = 0.f, a2 = 0.f, a3 = 0.f;
        const float4* hc = h4s + (chunk << 5);
        #pragma unroll
        for (int i = 0; i < 32; i += 4) {
            float4 h0 = hc[i], h1 = hc[i + 1], h2 = hc[i + 2], h3 = hc[i + 3];
            a0 = fmaf(w[i].x, h0.x, a0);     a0 = fmaf(w[i].y, h0.y, a0);
            a0 = fmaf(w[i].z, h0.z, a0);     a0 = fmaf(w[i].w, h0.w, a0);
            a1 = fmaf(w[i+1].x, h1.x, a1);   a1 = fmaf(w[i+1].y, h1.y, a1);
            a1 = fmaf(w[i+1].z, h1.z, a1);   a1 = fmaf(w[i+1].w, h1.w, a1);
            a2 = fmaf(w[i+2].x, h2.x, a2);   a2 = fmaf(w[i+2].y, h2.y, a2);
            a2 = fmaf(w[i+2].z, h2.z, a2);   a2 = fmaf(w[i+2].w, h2.w, a2);
            a3 = fmaf(w[i+3].x, h3.x, a3);   a3 = fmaf(w[i+3].y, h3.y, a3);
            a3 = fmaf(w[i+3].z, h3.z, a3);   a3 = fmaf(w[i+3].w, h3.w, a3);
        }
        part[chunk * 33 + tr] = (a0 + a1) + (a2 + a3);
        __syncthreads();

        if (tid < 32) {
            float v = gpre;
            #pragma unroll
            for (int k = 0; k < 8; ++k) v += part[k * 33 + tid];
            bool isg = (tid >> 3) == 2;           // gate g -> tanh
            float s = isg ? 2.f : 1.f;
            float e = __expf(-s * v);
            float r = 1.f / (1.f + e);
            float a = isg ? 2.f * r - 1.f : r;
            float si = __shfl(a, (tid & 7) + 0);
            float sf = __shfl(a, (tid & 7) + 8);
            float tg = __shfl(a, (tid & 7) + 16);
            float so = __shfl(a, (tid & 7) + 24);
            if (tid < 8) {
                float cnew = sf * cprev + si * tg;
                float e2 = __expf(-2.f * cnew);
                float hnew = so * (2.f / (1.f + e2) - 1.f);
                cprev = cnew;
                int j = j0 + tid;
                STA(&hio[(size_t)t * 2048 + cell * 1024 + j], hnew);
                if (it == SEQ - 1) {
                    STA(&finh[j], hnew);
                    STA(&finc[j], cnew);
                }
            }
            if (tid == 0)   // fire-and-forget: consumed only by GEMM-1 gating
                STA(&myflags[gblk * 4], (unsigned)(it + 1));
        }
    }
}

// ---------------- Fused pipeline kernel -------------------------------------
// 512 cooperative blocks, 2/CU. Blocks [0,256): recurrence (layer0 then
// layer1, setprio 1). Blocks [256,512): GEMM workers streaming G0 then G1 in
// 64x64 tiles. G1 pair k = (fwd rc=k, bwd rc=7-k) becomes available at
// recur-0 step max(64k+64, 512-64k); korder lists pairs by availability so
// each worker's gated list is monotone -> middle chunks stream DURING recur0.
// G1 reuses G0's buffers: the readiness gate also proves the overwritten G0
// chunk was consumed.
__constant__ int korder[8] = {3, 4, 2, 5, 1, 6, 0, 7};

__global__ __launch_bounds__(256, 2) void lstm_fused(
    const float* __restrict__ x,
    const float* __restrict__ w_ih0f, const float* __restrict__ w_hh0f, const float* __restrict__ b0f,
    const float* __restrict__ w_ih0b, const float* __restrict__ w_hh0b, const float* __restrict__ b0b,
    const float* __restrict__ w_ih1f, const float* __restrict__ w_hh1f, const float* __restrict__ b1f,
    const float* __restrict__ w_ih1b, const float* __restrict__ w_hh1b, const float* __restrict__ b1b,
    float* __restrict__ G0f, float* __restrict__ G0b,
    float* __restrict__ hist, float* __restrict__ h1buf,
    float* __restrict__ out,
    unsigned* __restrict__ flags0, unsigned* __restrict__ flags1,
    unsigned* __restrict__ g0cnt, unsigned* __restrict__ g1cnt)
{
    __shared__ float4 h4s[256];
    __shared__ float part[8 * 33];
    __shared__ float Xs[16][68];
    __shared__ float Ws[16][68];

    int bid = blockIdx.x;
    if (bid < NRECUR) {
        __builtin_amdgcn_s_setprio(1);   // keep recurrence issue priority
        int cell = (bid >> 7) & 1;
        int gblk = bid & 127;
        recur_cell(cell ? G0b : G0f, cell ? w_hh0b : w_hh0f, hist,
                   out + cell * 1024, out + 4096 + cell * 1024,
                   flags0 + cell * 512, g0cnt + cell * 8, cell, gblk, h4s, part);
        recur_cell(cell ? G0b : G0f, cell ? w_hh1b : w_hh1f, h1buf,   // G1 aliases G0
                   out + 2048 + cell * 1024, out + 4096 + 2048 + cell * 1024,
                   flags1 + cell * 512, g1cnt + cell * 8, cell, gblk, h4s, part);
    } else {
        int gid = bid - NRECUR;
        // G0: no input gate (x is a kernel input); ends-first order
        for (int idx = gid; idx < 1024; idx += NGEMM) {
            int k = idx >> 7, half = (idx >> 6) & 1, cc = idx & 63;
            int rc = half ? (7 - k) : k;
            gemm_tile<false>(x, half ? w_ih0b : w_ih0f, half ? b0b : b0f,
                             half ? G0b : G0f, rc * 64, cc * 64, 1024, Xs, Ws);
            __hip_atomic_fetch_add(&g0cnt[half * 8 + rc], 1u,
                                   __ATOMIC_RELEASE, __HIP_MEMORY_SCOPE_AGENT);
        }
        // G1: gated on recur-0 progress; availability order (korder)
        for (int idx = gid; idx < 1024; idx += NGEMM) {
            int k = korder[idx >> 7], half = (idx >> 6) & 1, cc = idx & 63;
            int rc = half ? (7 - k) : k;
            wait_outs0(flags0, rc);
            gemm_tile<true>(hist, half ? w_ih1b : w_ih1f, half ? b1b : b1f,
                            half ? G0b : G0f, rc * 64, cc * 64, 2048, Xs, Ws);
            __hip_atomic_fetch_add(&g1cnt[half * 8 + rc], 1u,
                                   __ATOMIC_RELEASE, __HIP_MEMORY_SCOPE_AGENT);
        }
    }
}

// ================= Fallback path (proven 4-kernel version) ==================
__global__ __launch_bounds__(256) void gemm_bias2(
    const float* __restrict__ X,
    const float* __restrict__ Wf, const float* __restrict__ Wb,
    const float* __restrict__ biasf, const float* __restrict__ biasb,
    float* __restrict__ Gf, float* __restrict__ Gb,
    int M, int N, int K)
{
    const float* W    = blockIdx.z ? Wb : Wf;
    const float* bias = blockIdx.z ? biasb : biasf;
    float*       G    = blockIdx.z ? Gb : Gf;
    __shared__ float Xs[16][68];
    __shared__ float Ws[16][68];
    int tid = threadIdx.x;
    int tx = tid & 15, ty = tid >> 4;
    int m0 = blockIdx.y * 64, n0 = blockIdx.x * 64;
    float acc[4][4] = {};
    for (int k0 = 0; k0 < K; k0 += 16) {
        int row = tid >> 2, kq = (tid & 3) << 2;
        float4 vx = *(const float4*)(X + (size_t)(m0 + row) * K + k0 + kq);
        Xs[kq + 0][row] = vx.x; Xs[kq + 1][row] = vx.y;
        Xs[kq + 2][row] = vx.z; Xs[kq + 3][row] = vx.w;
        float4 vw = *(const float4*)(W + (size_t)(n0 + row) * K + k0 + kq);
        Ws[kq + 0][row] = vw.x; Ws[kq + 1][row] = vw.y;
        Ws[kq + 2][row] = vw.z; Ws[kq + 3][row] = vw.w;
        __syncthreads();
        #pragma unroll
        for (int k = 0; k < 16; ++k) {
            float4 av = *(const float4*)&Xs[k][ty * 4];
            float4 bv = *(const float4*)&Ws[k][tx * 4];
            float a[4] = {av.x, av.y, av.z, av.w};
            float b[4] = {bv.x, bv.y, bv.z, bv.w};
            #pragma unroll
            for (int i = 0; i < 4; ++i)
                #pragma unroll
                for (int j = 0; j < 4; ++j)
                    acc[i][j] = fmaf(a[i], b[j], acc[i][j]);
        }
        __syncthreads();
    }
    #pragma unroll
    for (int i = 0; i < 4; ++i) {
        int m = m0 + ty * 4 + i;
        #pragma unroll
        for (int j = 0; j < 4; ++j) {
            int n = n0 + tx * 4 + j;
            G[(size_t)m * N + n] = acc[i][j] + bias[n];
        }
    }
}

__global__ __launch_bounds__(256, 1) void lstm_recur(
    const float* __restrict__ Gf, const float* __restrict__ Gb,
    const float* __restrict__ Whf, const float* __restrict__ Whb,
    float* __restrict__ hist, float* __restrict__ h1buf,
    float* __restrict__ fin_h, float* __restrict__ fin_c,
    unsigned* __restrict__ flags, int layer)
{
    __shared__ float4 h4s[256];
    __shared__ float part[8 * 33];
    __shared__ float c_s[8];

    int tid = threadIdx.x;
    int cell = blockIdx.x >> 7;
    int gblk = blockIdx.x & 127;
    int j0 = gblk << 3;

    const float* Wh  = cell ? Whb : Whf;
    const float* Gin = cell ? Gb  : Gf;
    unsigned* myflags = flags + cell * 512;
    float* hout = (layer == 0) ? hist : h1buf;

    int tr = tid & 31, chunk = tid >> 5;
    int grow = ((tr >> 3) << 10) + j0 + (tr & 7);

    const float4* wrow = (const float4*)(Wh + (size_t)grow * 1024) + (chunk << 5);
    float4 w[32];
    #pragma unroll
    for (int i = 0; i < 32; ++i) w[i] = wrow[i];
    #pragma unroll
    for (int i = 0; i < 32; ++i)
        asm volatile("" : "+v"(w[i].x), "+v"(w[i].y), "+v"(w[i].z), "+v"(w[i].w));

    if (tid < 8) c_s[tid] = 0.f;

    for (int it = 0; it < SEQ; ++it) {
        int t = cell ? (SEQ - 1 - it) : it;
        float gpre = 0.f;
        if (tid < 32) gpre = Gin[(size_t)t * 4096 + grow];

        if (it == 0) {
            h4s[tid] = make_float4(0.f, 0.f, 0.f, 0.f);
        } else {
            if (tid < 64) {
                const unsigned* f0 = myflags + tid * 4;
                const unsigned* f1 = myflags + 256 + tid * 4;
                unsigned tgt = (unsigned)it;
                for (;;) {
                    unsigned a = LDA(f0);
                    unsigned b = LDA(f1);
                    if (__all(a >= tgt && b >= tgt)) break;
                    __builtin_amdgcn_s_sleep(1);
                }
            }
            __syncthreads();
            const float* hp;
            if (layer == 0)
                hp = cell ? (hist + (size_t)(t + 1) * 2048 + 1024)
                          : (hist + (size_t)(t - 1) * 2048);
            else
                hp = cell ? (h1buf + (size_t)(t + 1) * 2048 + 1024)
                          : (h1buf + (size_t)(t - 1) * 2048);
            const unsigned long long* hp64 = (const unsigned long long*)hp;
            unsigned long long u0, u1;
            for (;;) {
                u0 = LDA(hp64 + 2 * tid);
                u1 = LDA(hp64 + 2 * tid + 1);
                if (!(has_can(u0) | has_can(u1))) break;
            }
            h4s[tid] = make_float4(__uint_as_float((unsigned)u0),
                                   __uint_as_float((unsigned)(u0 >> 32)),
                                   __uint_as_float((unsigned)u1),
                                   __uint_as_float((unsigned)(u1 >> 32)));
        }
        __syncthreads();

        float a0 = 0.f, a1 = 0.f, a2 = 0.f, a3 = 0.f;
        const float4* hc = (const float4*)h4s + (chunk << 5);
        #pragma unroll
        for (int i = 0; i < 32; i += 4) {
            float4 h0 = hc[i], h1 = hc[i + 1], h2 = hc[i + 2], h3 = hc[i + 3];
            a0 = fmaf(w[i].x, h0.x, a0);     a0 = fmaf(w[i].y, h0.y, a0);
            a0 = fmaf(w[i].z, h0.z, a0);     a0 = fmaf(w[i].w, h0.w, a0);
            a1 = fmaf(w[i+1].x, h1.x, a1);   a1 = fmaf(w[i+1].y, h1.y, a1);
            a1 = fmaf(w[i+1].z, h1.z, a1);   a1 = fmaf(w[i+1].w, h1.w, a1);
            a2 = fmaf(w[i+2].x, h2.x, a2);   a2 = fmaf(w[i+2].y, h2.y, a2);
            a2 = fmaf(w[i+2].z, h2.z, a2);   a2 = fmaf(w[i+2].w, h2.w, a2);
            a3 = fmaf(w[i+3].x, h3.x, a3);   a3 = fmaf(w[i+3].y, h3.y, a3);
            a3 = fmaf(w[i+3].z, h3.z, a3);   a3 = fmaf(w[i+3].w, h3.w, a3);
        }
        part[chunk * 33 + tr] = (a0 + a1) + (a2 + a3);
        __syncthreads();

        if (tid < 32) {
            float v = gpre;
            #pragma unroll
            for (int k = 0; k < 8; ++k) v += part[k * 33 + tid];
            bool isg = (tid >> 3) == 2;
            float s = isg ? 2.f : 1.f;
            float e = __expf(-s * v);
            float r = 1.f / (1.f + e);
            float a = isg ? 2.f * r - 1.f : r;
            float si = __shfl(a, (tid & 7) + 0);
            float sf = __shfl(a, (tid & 7) + 8);
            float tg = __shfl(a, (tid & 7) + 16);
            float so = __shfl(a, (tid & 7) + 24);
            if (tid < 8) {
                float cnew = sf * c_s[tid] + si * tg;
                float e2 = __expf(-2.f * cnew);
                float hnew = so * (2.f / (1.f + e2) - 1.f);
                c_s[tid] = cnew;
                int j = j0 + tid;
                STA(&hout[(size_t)t * 2048 + cell * 1024 + j], hnew);
                if (it == SEQ - 1) {
                    STA(&fin_h[cell * 1024 + j], hnew);
                    STA(&fin_c[cell * 1024 + j], cnew);
                }
            }
            if (tid == 0 && it < SEQ - 1)
                STA(&myflags[gblk * 4], (unsigned)(it + 1));
        }
    }
}

// ---------------- launch ----------------
extern "C" void kernel_launch(void* const* d_in, const int* in_sizes, int n_in,
                              void* d_out, int out_size, void* d_ws, size_t ws_size,
                              hipStream_t stream) {
    const float* x      = (const float*)d_in[0];
    const float* w_ih0f = (const float*)d_in[1];
    const float* w_hh0f = (const float*)d_in[2];
    const float* b0f    = (const float*)d_in[3];
    const float* w_ih0b = (const float*)d_in[4];
    const float* w_hh0b = (const float*)d_in[5];
    const float* b0b    = (const float*)d_in[6];
    const float* w_ih1f = (const float*)d_in[7];
    const float* w_hh1f = (const float*)d_in[8];
    const float* b1f    = (const float*)d_in[9];
    const float* w_ih1b = (const float*)d_in[10];
    const float* w_hh1b = (const float*)d_in[11];
    const float* b1b    = (const float*)d_in[12];

    float* out   = (float*)d_out;
    float* outs0 = out + 8192;                 // [512,2048] == hist
    float* ws    = (float*)d_ws;
    float* G0f   = ws;                         // [512,4096]; G1f aliases after gate
    float* G0b   = ws + (size_t)512 * 4096;
    float* h1buf = ws + (size_t)2 * 512 * 4096;               // [512][2048]
    unsigned* flagbase = (unsigned*)(h1buf + (size_t)512 * 2048);
    unsigned* flags0 = flagbase;          // 1024 words
    unsigned* flags1 = flagbase + 1024;   // 1024 words
    unsigned* g0cnt  = flagbase + 2048;   // 16 chunk counters (cell*8+rc)
    unsigned* g1cnt  = flagbase + 2064;   // 16

    hipLaunchKernelGGL(init_bufs, dim3(1024), dim3(256), 0, stream,
                       flagbase, (unsigned*)outs0, (unsigned*)h1buf);

    int occ = 0;
    hipOccupancyMaxActiveBlocksPerMultiprocessor(&occ, lstm_fused, 256, 0);

    hipError_t lerr = hipErrorUnknown;
    if (occ >= 2) {
        // fused pipeline: one cooperative kernel, 512 blocks (2/CU)
        const float* xp = x;
        const float* a1 = w_ih0f; const float* a2 = w_hh0f; const float* a3 = b0f;
        const float* a4 = w_ih0b; const float* a5 = w_hh0b; const float* a6 = b0b;
        const float* a7 = w_ih1f; const float* a8 = w_hh1f; const float* a9 = b1f;
        const float* aa = w_ih1b; const float* ab = w_hh1b; const float* ac = b1b;
        float* g0fp = G0f; float* g0bp = G0b;
        float* histp = outs0; float* h1p = h1buf; float* outp = out;
        unsigned* f0p = flags0; unsigned* f1p = flags1;
        unsigned* c0p = g0cnt;  unsigned* c1p = g1cnt;
        void* args[] = {(void*)&xp,
                        (void*)&a1, (void*)&a2, (void*)&a3,
                        (void*)&a4, (void*)&a5, (void*)&a6,
                        (void*)&a7, (void*)&a8, (void*)&a9,
                        (void*)&aa, (void*)&ab, (void*)&ac,
                        (void*)&g0fp, (void*)&g0bp,
                        (void*)&histp, (void*)&h1p, (void*)&outp,
                        (void*)&f0p, (void*)&f1p, (void*)&c0p, (void*)&c1p};
        lerr = hipLaunchCooperativeKernel((void*)lstm_fused, dim3(NRECUR + NGEMM),
                                          dim3(256), args, 0, stream);
    }
    if (occ < 2 || lerr != hipSuccess) {
        // fallback: proven serial 4-kernel pipeline
        float* G1f = ws;
        float* G1b = ws + (size_t)512 * 4096;
        dim3 gb(64, 8, 2), tb(256);
        hipLaunchKernelGGL(gemm_bias2, gb, tb, 0, stream,
                           x, w_ih0f, w_ih0b, b0f, b0b, G0f, G0b, 512, 4096, 1024);
        {
            int layer = 0;
            const float* Gfp = G0f; const float* Gbp = G0b;
            const float* Whf = w_hh0f; const float* Whb = w_hh0b;
            float* hist = outs0; float* h1 = h1buf;
            float* finh = out;
            float* finc = out + 4096;
            unsigned* fl = flags0;
            void* args[] = {(void*)&Gfp, (void*)&Gbp, (void*)&Whf, (void*)&Whb,
                            (void*)&hist, (void*)&h1, (void*)&finh, (void*)&finc,
                            (void*)&fl, (void*)&layer};
            hipLaunchCooperativeKernel((void*)lstm_recur, dim3(256), dim3(256), args, 0, stream);
        }
        hipLaunchKernelGGL(gemm_bias2, gb, tb, 0, stream,
                           outs0, w_ih1f, w_ih1b, b1f, b1b, G1f, G1b, 512, 4096, 2048);
        {
            int layer = 1;
            const float* Gfp = G1f; const float* Gbp = G1b;
            const float* Whf = w_hh1f; const float* Whb = w_hh1b;
            float* hist = outs0; float* h1 = h1buf;
            float* finh = out + 2048;
            float* finc = out + 4096 + 2048;
            unsigned* fl = flags1;
            void* args[] = {(void*)&Gfp, (void*)&Gbp, (void*)&Whf, (void*)&Whb,
                            (void*)&hist, (void*)&h1, (void*)&finh, (void*)&finc,
                            (void*)&fl, (void*)&layer};
            hipLaunchCooperativeKernel((void*)lstm_recur, dim3(256), dim3(256), args, 0, stream);
        }
    }
}